// Round 2
// baseline (1031.903 us; speedup 1.0000x reference)
//
#include <hip/hip_runtime.h>
#include <cstdint>
#include <cstddef>

#define D_MODEL 1024
#define D_FF    4096
#define N_EXPERTS 8
#define TOPK_    2
#define NTOK    8192
#define NSLOT   (NTOK*TOPK_)

// 256^2 quadrant-phase grouped-GEMM tile geometry
#define BM 256
#define BN 256
#define BK 64
#define MAXTILES 72   // sum ceil(count_e/256) <= 16384/256 + 8 = 72

typedef __attribute__((ext_vector_type(8))) short bf16x8;
typedef __attribute__((ext_vector_type(4))) float f32x4;
typedef unsigned int u32;

__device__ __forceinline__ unsigned short f2bf(float f){
  union { float f; u32 u; } v; v.f = f;
  u32 u = v.u;
  u32 r = (u + 0x7FFFu + ((u >> 16) & 1u)) >> 16;
  return (unsigned short)r;
}

__device__ __forceinline__ float bf2f(unsigned short s){
  union { u32 u; float f; } v; v.u = (u32)s << 16; return v.f;
}

// gelu via Abramowitz-Stegun 7.1.26 erf, |err| <= 1.5e-7 abs.
__device__ __forceinline__ float gelu_fast(float x){
  float z = fabsf(x) * 0.70710678118654752f;
  float t = __builtin_amdgcn_rcpf(fmaf(0.3275911f, z, 1.0f));
  float poly = t * (0.254829592f + t * (-0.284496736f + t * (1.421413741f +
               t * (-1.453152027f + t * 1.061405429f))));
  float e = __expf(-z * z);
  float erf_abs = fmaf(-poly, e, 1.0f);
  float erfv = copysignf(erf_abs, x);
  return 0.5f * x * (1.0f + erfv);
}

__device__ __forceinline__ void gload_lds16(const void* g, void* l){
  __builtin_amdgcn_global_load_lds(
      (const __attribute__((address_space(1))) u32*)g,
      (__attribute__((address_space(3))) u32*)l, 16, 0, 0);
}

// ---------------- weight transpose: [E][R][C] fp32 -> [E][C][R] bf16 ----------

__global__ __launch_bounds__(256) void transpose_convert_kernel(
    const float* __restrict__ in, unsigned short* __restrict__ out,
    int R, int C){
  __shared__ float tile[64][65];
  const int e  = blockIdx.z;
  const int c0 = blockIdx.x * 64;
  const int r0 = blockIdx.y * 64;
  const int tid = threadIdx.x;
  const size_t base = (size_t)e * R * C;
  {
    const int r  = tid >> 4;          // 0..15
    const int c4 = (tid & 15) * 4;    // 0..60
    #pragma unroll
    for (int it = 0; it < 4; it++){
      int rr = r + it * 16;
      float4 v = *(const float4*)(in + base + (size_t)(r0 + rr) * C + c0 + c4);
      tile[rr][c4 + 0] = v.x;
      tile[rr][c4 + 1] = v.y;
      tile[rr][c4 + 2] = v.z;
      tile[rr][c4 + 3] = v.w;
    }
  }
  __syncthreads();
  {
    const int c  = tid >> 4;          // 0..15
    const int r4 = (tid & 15) * 4;
    #pragma unroll
    for (int it = 0; it < 4; it++){
      int cc = c + it * 16;
      ushort4 w;
      w.x = f2bf(tile[r4 + 0][cc]);
      w.y = f2bf(tile[r4 + 1][cc]);
      w.z = f2bf(tile[r4 + 2][cc]);
      w.w = f2bf(tile[r4 + 3][cc]);
      *(ushort4*)(out + base + (size_t)(c0 + cc) * R + r0 + r4) = w;
    }
  }
}

// ---------------- router (also converts x -> bf16, single pass) --------------

__global__ __launch_bounds__(64) void router_kernel(
    const float* __restrict__ x,
    const float* __restrict__ Wr,
    const float* __restrict__ br,
    int* __restrict__ counts,
    int* __restrict__ topk_idx,
    float* __restrict__ topk_gate,
    unsigned short* __restrict__ xb){
  const int n = blockIdx.x;
  const int lane = threadIdx.x;      // 64 threads
  const float* xr = x + (size_t)n * D_MODEL;
  unsigned short* xbr = xb + (size_t)n * D_MODEL;
  float acc[N_EXPERTS];
  #pragma unroll
  for (int e = 0; e < N_EXPERTS; e++) acc[e] = 0.f;
  #pragma unroll
  for (int it = 0; it < 4; it++){
    int d = it * 256 + lane * 4;
    float4 v = *(const float4*)(xr + d);
    ushort4 w;
    w.x = f2bf(v.x); w.y = f2bf(v.y); w.z = f2bf(v.z); w.w = f2bf(v.w);
    *(ushort4*)(xbr + d) = w;
    const float* wr = Wr + (size_t)d * N_EXPERTS;
    const float* vv = &v.x;
    #pragma unroll
    for (int j = 0; j < 4; j++)
      #pragma unroll
      for (int e = 0; e < N_EXPERTS; e++)
        acc[e] = fmaf(vv[j], wr[j * N_EXPERTS + e], acc[e]);
  }
  #pragma unroll
  for (int e = 0; e < N_EXPERTS; e++){
    float v = acc[e];
    for (int o = 32; o > 0; o >>= 1) v += __shfl_xor(v, o, 64);
    acc[e] = v;
  }
  if (lane == 0){
    float logits[N_EXPERTS];
    float m = -1e30f;
    #pragma unroll
    for (int e = 0; e < N_EXPERTS; e++){
      logits[e] = acc[e] + br[e];
      m = fmaxf(m, logits[e]);
    }
    float p[N_EXPERTS]; float Z = 0.f;
    #pragma unroll
    for (int e = 0; e < N_EXPERTS; e++){ p[e] = expf(logits[e] - m); Z += p[e]; }
    #pragma unroll
    for (int e = 0; e < N_EXPERTS; e++) p[e] /= Z;
    int i0 = 0;
    #pragma unroll
    for (int e = 1; e < N_EXPERTS; e++) if (p[e] > p[i0]) i0 = e;
    int i1 = (i0 == 0) ? 1 : 0;
    #pragma unroll
    for (int e = 0; e < N_EXPERTS; e++){
      if (e == i0) continue;
      if (p[e] > p[i1]) i1 = e;
    }
    float s = p[i0] + p[i1] + 1e-9f;
    topk_idx[n * 2 + 0] = i0;
    topk_idx[n * 2 + 1] = i1;
    topk_gate[n * 2 + 0] = p[i0] / s;
    topk_gate[n * 2 + 1] = p[i1] / s;
    atomicAdd(&counts[i0], 1);
    atomicAdd(&counts[i1], 1);
  }
}

// ---------------- bookkeeping: offsets + tile table, parallel ----------------

__global__ __launch_bounds__(256) void prefix_kernel(
    const int* __restrict__ counts,
    int* __restrict__ offsets,
    int* __restrict__ cursor,
    int* __restrict__ tile_e,
    int* __restrict__ tile_m){
  __shared__ int scnt[N_EXPERTS];
  __shared__ int soff[N_EXPERTS];
  const int tid = threadIdx.x;
  if (tid < N_EXPERTS) scnt[tid] = counts[tid];
  __syncthreads();
  if (tid == 0){
    int o = 0;
    for (int e = 0; e < N_EXPERTS; e++){ soff[e] = o; o += scnt[e]; }
  }
  __syncthreads();
  if (tid < N_EXPERTS){ offsets[tid] = soff[tid]; cursor[tid] = soff[tid]; }
  if (tid < MAXTILES){
    int t = tid, te = -1, tm = 0, acc = 0;
    #pragma unroll
    for (int e = 0; e < N_EXPERTS; e++){
      int nt = (scnt[e] + BM - 1) / BM;
      if (te < 0 && t < acc + nt){ te = e; tm = t - acc; }
      acc += nt;
    }
    tile_e[tid] = te; tile_m[tid] = tm;
  }
}

__global__ void assign_kernel(const int* __restrict__ topk_idx,
                              const float* __restrict__ topk_gate,
                              int* __restrict__ cursor,
                              int* __restrict__ bucket_token,
                              float* __restrict__ bucket_gate,
                              int* __restrict__ slot_of){
  int n = blockIdx.x * blockDim.x + threadIdx.x;
  if (n >= NTOK) return;
  #pragma unroll
  for (int k = 0; k < TOPK_; k++){
    int e = topk_idx[n * 2 + k];
    float g = topk_gate[n * 2 + k];
    int s = atomicAdd(&cursor[e], 1);
    bucket_token[s] = n;
    bucket_gate[s] = g;
    slot_of[n * 2 + k] = s;
  }
}

// ---------------- grouped GEMM, 256^2 tile, quadrant-phase schedule ----------
//
// All 8 waves compute the SAME 128x128 C-quadrant per phase, Gray order:
//   q0:(Ah0,Bh0)  q1:(Ah0,Bh1)  q2:(Ah1,Bh1)  q3:(Ah1,Bh0)
// so A/B half-tiles are consumed at staggered phases. Staging ledger
// (tile t stages t+1 into the other buffer; 2 gloads per SA_/SB_):
//   t.q0: stage {Ah0,Bh0}(t+1); VMW(4) drains {Ah1,Bh1}(t)   [issued t-1.q1, 3 phases back]
//   t.q1: stage {Ah1,Bh1}(t+1)
//   t.q3: VMW(4) drains {Ah0,Bh0}(t+1)                        [issued t.q0, 3 phases back]
// Outstanding oscillates 4<->8 loads; never vmcnt(0) in the main loop.
// One barrier per phase (after VMW, before MFMA) + a tile-boundary closing
// barrier protecting buf[cur] reads before t+1.q0 overwrites it.
// Gray order reuses one operand's fragments between phases: 28 ds_read_b128
// per tile instead of 48. XOR column swizzle (bank-conflict PMC-verified 0).

#define BARR do { asm volatile("" ::: "memory"); \
                  __builtin_amdgcn_s_barrier(); \
                  asm volatile("" ::: "memory"); } while(0)
#define VMW(n) asm volatile("s_waitcnt vmcnt(" #n ")" ::: "memory")

// stage A half-tile (half=0: rows 0-127, half=1: rows 128-255) at k offset
#define SA_(bufi, half, k) do { \
  gload_lds16(asrc[2*(half)]   + (k), &As[bufi][(2*(half))*64   + (tid>>3)][(tid&7)*8]); \
  gload_lds16(asrc[2*(half)+1] + (k), &As[bufi][(2*(half)+1)*64 + (tid>>3)][(tid&7)*8]); \
} while(0)
#define SB_(bufi, half, k) do { \
  gload_lds16(bsrc[2*(half)]   + (k), &Bs[bufi][(2*(half))*64   + (tid>>3)][(tid&7)*8]); \
  gload_lds16(bsrc[2*(half)+1] + (k), &Bs[bufi][(2*(half)+1)*64 + (tid>>3)][(tid&7)*8]); \
} while(0)

// load A fragments for quadrant row-half qm (4 M-frags x 2 k-slices)
#define LDA_(bc, qm) do { \
  _Pragma("unroll") \
  for (int i_ = 0; i_ < 4; i_++){ \
    const int r_ = (qm)*128 + rw*64 + i_*16 + fm; \
    a[i_][0] = *(const bf16x8*)&As[bc][r_][ck0]; \
    a[i_][1] = *(const bf16x8*)&As[bc][r_][ck1]; \
  } \
} while(0)
// load B fragments for quadrant col-half qn (2 N-frags x 2 k-slices)
#define LDB_(bc, qn) do { \
  _Pragma("unroll") \
  for (int j_ = 0; j_ < 2; j_++){ \
    const int r_ = (qn)*128 + cw*32 + j_*16 + fm; \
    b[j_][0] = *(const bf16x8*)&Bs[bc][r_][ck0]; \
    b[j_][1] = *(const bf16x8*)&Bs[bc][r_][ck1]; \
  } \
} while(0)

#define MFQ(qm, qn) do { \
  __builtin_amdgcn_s_setprio(1); \
  _Pragma("unroll") \
  for (int i_ = 0; i_ < 4; i_++) \
    _Pragma("unroll") \
    for (int j_ = 0; j_ < 2; j_++){ \
      acc[qm][qn][i_][j_] = __builtin_amdgcn_mfma_f32_16x16x32_bf16(a[i_][0], b[j_][0], acc[qm][qn][i_][j_], 0, 0, 0); \
      acc[qm][qn][i_][j_] = __builtin_amdgcn_mfma_f32_16x16x32_bf16(a[i_][1], b[j_][1], acc[qm][qn][i_][j_], 0, 0, 0); \
    } \
  __builtin_amdgcn_s_setprio(0); \
} while(0)

// full tile body: read buf bc, stage next tile into buf bn_ at k offset kn
#define TILE_Q(bc, bn_, kn) do { \
  LDA_(bc,0); LDB_(bc,0); \
  SA_(bn_,0,(kn)); SB_(bn_,0,(kn)); \
  VMW(4); BARR; \
  MFQ(0,0); \
  LDB_(bc,1); \
  SA_(bn_,1,(kn)); SB_(bn_,1,(kn)); \
  BARR; \
  MFQ(0,1); \
  LDA_(bc,1); \
  BARR; \
  MFQ(1,1); \
  LDB_(bc,0); \
  VMW(4); BARR; \
  MFQ(1,0); \
  BARR; \
} while(0)

// tail tile: no staging
#define TILE_T(bc) do { \
  LDA_(bc,0); LDB_(bc,0); \
  VMW(0); BARR; \
  MFQ(0,0); \
  LDB_(bc,1); \
  BARR; \
  MFQ(0,1); \
  LDA_(bc,1); \
  BARR; \
  MFQ(1,1); \
  LDB_(bc,0); \
  BARR; \
  MFQ(1,0); \
} while(0)

// MODE 0: gemm1  h = gelu(xb[token] @ W1t + b1)     (KDIM=1024, NDIM=4096)
// MODE 1: gemm2  y = g * (hb[slot] @ W2t + b2)      (KDIM=4096, NDIM=1024)
template<int KDIM, int NDIM, int MODE>
__global__ __launch_bounds__(512, 2) void moe_gemm_kernel(
    const unsigned short* __restrict__ A,
    const unsigned short* __restrict__ Wt,
    const float* __restrict__ bias_g,
    const int* __restrict__ bucket_token,
    const float* __restrict__ bucket_gate,
    const int* __restrict__ offsets,
    const int* __restrict__ counts,
    const int* __restrict__ tile_e,
    const int* __restrict__ tile_m,
    unsigned short* __restrict__ out){
  const int e = tile_e[blockIdx.y];
  if (e < 0) return;
  const int mtile = tile_m[blockIdx.y];
  const int ntile = blockIdx.x;
  const int count = counts[e];
  const int off = offsets[e];

  __shared__ unsigned short As[2][BM][BK];   // 64 KB
  __shared__ unsigned short Bs[2][BN][BK];   // 64 KB

  const int tid  = threadIdx.x;
  const int lane = tid & 63;
  const int wave = tid >> 6;          // 8 waves: 2 (qrow) x 4 (qcol)
  const int rw = wave >> 2;           // 0..1: 64-row block within quadrant
  const int cw = wave & 3;            // 0..3: 32-col block within quadrant
  const int fm = lane & 15;
  // swizzled k-column element offsets for the two k-subtiles (kk=0,32)
  const int ck0 = (((lane >> 4)    ) ^ (lane & 7)) * 8;
  const int ck1 = (((lane >> 4) + 4) ^ (lane & 7)) * 8;
  // staging: thread covers row (c*64 + tid>>3), LDS colgrp tid&7,
  // global colgrp (tid&7)^((tid>>3)&7)  [LDS[r][c] = global[r][c ^ (r&7)]]
  const int cg = ((tid & 7) ^ ((tid >> 3) & 7)) * 8;

  const unsigned short* asrc[4];
  const unsigned short* bsrc[4];
  #pragma unroll
  for (int c = 0; c < 4; c++){
    int m = mtile * BM + c * 64 + (tid >> 3);
    int mm = min(m, count - 1);
    size_t arow = (MODE == 0) ? (size_t)bucket_token[off + mm] : (size_t)(off + mm);
    asrc[c] = A + arow * KDIM + cg;
    bsrc[c] = Wt + ((size_t)e * NDIM + (size_t)ntile * BN + c * 64 + (tid >> 3)) * KDIM + cg;
  }

  const f32x4 zero = {0.f, 0.f, 0.f, 0.f};
  f32x4 acc[2][2][4][2];
  #pragma unroll
  for (int qm = 0; qm < 2; qm++)
    #pragma unroll
    for (int qn = 0; qn < 2; qn++)
      #pragma unroll
      for (int i = 0; i < 4; i++)
        #pragma unroll
        for (int j = 0; j < 2; j++) acc[qm][qn][i][j] = zero;

  bf16x8 a[4][2], b[2][2];

  // ---- prologue: stage tile0 fully (8 loads), wait first 4 (Ah0,Bh0) ----
  SA_(0,0,0); SB_(0,0,0);
  SA_(0,1,0); SB_(0,1,0);
  VMW(4); BARR;

  // NT = KDIM/BK is even (16 or 64). Pairs cover tiles 0..NT-3, then a
  // full tile NT-2 (buf0) and the tail tile NT-1 (buf1).
  int k = 0;
  #pragma unroll 1
  for (int tp = 0; tp < (KDIM/BK - 2) / 2; ++tp){
    TILE_Q(0, 1, k + BK);
    TILE_Q(1, 0, k + 2*BK);
    k += 2*BK;
  }
  TILE_Q(0, 1, k + BK);
  TILE_T(1);

  // ---- epilogue ----
  const float* bias = bias_g + (size_t)e * NDIM + (size_t)ntile * BN;
  float bj[2][2];
  #pragma unroll
  for (int qn = 0; qn < 2; qn++)
    #pragma unroll
    for (int j = 0; j < 2; j++)
      bj[qn][j] = bias[qn*128 + cw*32 + j*16 + fm];

  #pragma unroll
  for (int qm = 0; qm < 2; qm++){
    #pragma unroll
    for (int i = 0; i < 4; i++){
      #pragma unroll
      for (int r = 0; r < 4; r++){
        int mrel = qm*128 + rw*64 + i*16 + (lane >> 4) * 4 + r;
        int m = mtile * BM + mrel;
        if (m >= count) continue;
        int slot = off + m;
        unsigned short* orow = out + (size_t)slot * NDIM + (size_t)ntile * BN;
        if constexpr (MODE == 0){
          #pragma unroll
          for (int qn = 0; qn < 2; qn++)
            #pragma unroll
            for (int j = 0; j < 2; j++){
              float v = acc[qm][qn][i][j][r] + bj[qn][j];
              orow[qn*128 + cw*32 + j*16 + fm] = f2bf(gelu_fast(v));
            }
        } else {
          float g = bucket_gate[slot];
          #pragma unroll
          for (int qn = 0; qn < 2; qn++)
            #pragma unroll
            for (int j = 0; j < 2; j++){
              float v = g * (acc[qm][qn][i][j][r] + bj[qn][j]);
              orow[qn*128 + cw*32 + j*16 + fm] = f2bf(v);
            }
        }
      }
    }
  }
}

// ---------------- combine: out[t] = y[slot0(t)] + y[slot1(t)] ----------------

__global__ __launch_bounds__(256) void combine_kernel(
    const unsigned short* __restrict__ y,
    const int* __restrict__ slot_of,
    float* __restrict__ out){
  const int t = blockIdx.x;
  const int d = threadIdx.x * 4;
  const int s0 = slot_of[t * 2 + 0];
  const int s1 = slot_of[t * 2 + 1];
  uint2 a = *(const uint2*)(y + (size_t)s0 * D_MODEL + d);
  uint2 b = *(const uint2*)(y + (size_t)s1 * D_MODEL + d);
  float4 r;
  r.x = bf2f((unsigned short)(a.x & 0xffff)) + bf2f((unsigned short)(b.x & 0xffff));
  r.y = bf2f((unsigned short)(a.x >> 16))    + bf2f((unsigned short)(b.x >> 16));
  r.z = bf2f((unsigned short)(a.y & 0xffff)) + bf2f((unsigned short)(b.y & 0xffff));
  r.w = bf2f((unsigned short)(a.y >> 16))    + bf2f((unsigned short)(b.y >> 16));
  *(float4*)(out + (size_t)t * D_MODEL + d) = r;
}

// ---------------- launch ----------------

extern "C" void kernel_launch(void* const* d_in, const int* in_sizes, int n_in,
                              void* d_out, int out_size, void* d_ws, size_t ws_size,
                              hipStream_t stream) {
  (void)in_sizes; (void)n_in; (void)ws_size; (void)out_size;
  const float* x  = (const float*)d_in[0];
  const float* Wr = (const float*)d_in[1];
  const float* br = (const float*)d_in[2];
  const float* W1 = (const float*)d_in[3];
  const float* b1 = (const float*)d_in[4];
  const float* W2 = (const float*)d_in[5];
  const float* b2 = (const float*)d_in[6];
  float* out = (float*)d_out;

  char* ws = (char*)d_ws;
  size_t p = 0;
  auto alloc = [&](size_t bytes) -> void* {
    void* r = ws + p;
    p = (p + bytes + 255) & ~(size_t)255;
    return r;
  };

  int*   counts       = (int*)  alloc(N_EXPERTS * sizeof(int));
  int*   offsets      = (int*)  alloc(N_EXPERTS * sizeof(int));
  int*   cursor       = (int*)  alloc(N_EXPERTS * sizeof(int));
  int*   tile_e       = (int*)  alloc(MAXTILES * sizeof(int));
  int*   tile_m       = (int*)  alloc(MAXTILES * sizeof(int));
  int*   topk_idx     = (int*)  alloc((size_t)NTOK * 2 * sizeof(int));
  float* topk_gate    = (float*)alloc((size_t)NTOK * 2 * sizeof(float));
  int*   bucket_token = (int*)  alloc((size_t)NSLOT * sizeof(int));
  float* bucket_gate  = (float*)alloc((size_t)NSLOT * sizeof(float));
  int*   slot_of      = (int*)  alloc((size_t)NTOK * 2 * sizeof(int));
  unsigned short* xb  = (unsigned short*)alloc((size_t)NTOK * D_MODEL * 2);
  unsigned short* W1t = (unsigned short*)alloc((size_t)N_EXPERTS * D_MODEL * D_FF * 2);
  unsigned short* W2t = (unsigned short*)alloc((size_t)N_EXPERTS * D_MODEL * D_FF * 2);
  unsigned short* hb  = (unsigned short*)alloc((size_t)NSLOT * D_FF * 2);
  // y (bf16, 32 MB) aliases W1t (64 MB): W1t is dead once gemm1 completes.
  unsigned short* y = W1t;

  hipMemsetAsync(counts, 0, N_EXPERTS * sizeof(int), stream);

  // Transposes FIRST so nothing streams between gemm1 and gemm2 (keeps h
  // L3-resident for gemm2), and gemm1 reads recently-written xb/W1t.
  transpose_convert_kernel<<<dim3(D_MODEL / 64, D_FF / 64, N_EXPERTS), 256, 0, stream>>>(
      W2, W2t, D_FF, D_MODEL);
  transpose_convert_kernel<<<dim3(D_FF / 64, D_MODEL / 64, N_EXPERTS), 256, 0, stream>>>(
      W1, W1t, D_MODEL, D_FF);
  router_kernel<<<NTOK, 64, 0, stream>>>(x, Wr, br, counts, topk_idx, topk_gate, xb);
  prefix_kernel<<<1, 256, 0, stream>>>(counts, offsets, cursor, tile_e, tile_m);
  assign_kernel<<<NTOK / 256, 256, 0, stream>>>(topk_idx, topk_gate, cursor,
                                                bucket_token, bucket_gate, slot_of);
  moe_gemm_kernel<D_MODEL, D_FF, 0><<<dim3(D_FF / BN, MAXTILES), 512, 0, stream>>>(
      xb, W1t, b1, bucket_token, nullptr, offsets, counts, tile_e, tile_m, hb);
  moe_gemm_kernel<D_FF, D_MODEL, 1><<<dim3(D_MODEL / BN, MAXTILES), 512, 0, stream>>>(
      hb, W2t, b2, nullptr, bucket_gate, offsets, counts, tile_e, tile_m, y);
  combine_kernel<<<NTOK, 256, 0, stream>>>(y, slot_of, out);
}

// Round 3
// 1016.408 us; speedup vs baseline: 1.0152x; 1.0152x over previous
//
#include <hip/hip_runtime.h>
#include <cstdint>
#include <cstddef>

#define D_MODEL 1024
#define D_FF    4096
#define N_EXPERTS 8
#define TOPK_    2
#define NTOK    8192
#define NSLOT   (NTOK*TOPK_)

// 256^2 8-phase grouped-GEMM tile geometry
#define BM 256
#define BN 256
#define BK 64
#define MAXTILES 72   // sum ceil(count_e/256) <= 16384/256 + 8 = 72

typedef __attribute__((ext_vector_type(8))) short bf16x8;
typedef __attribute__((ext_vector_type(4))) float f32x4;
typedef unsigned int u32;

__device__ __forceinline__ unsigned short f2bf(float f){
  union { float f; u32 u; } v; v.f = f;
  u32 u = v.u;
  u32 r = (u + 0x7FFFu + ((u >> 16) & 1u)) >> 16;
  return (unsigned short)r;
}

__device__ __forceinline__ float bf2f(unsigned short s){
  union { u32 u; float f; } v; v.u = (u32)s << 16; return v.f;
}

// gelu via Abramowitz-Stegun 7.1.26 erf, |err| <= 1.5e-7 abs.
__device__ __forceinline__ float gelu_fast(float x){
  float z = fabsf(x) * 0.70710678118654752f;
  float t = __builtin_amdgcn_rcpf(fmaf(0.3275911f, z, 1.0f));
  float poly = t * (0.254829592f + t * (-0.284496736f + t * (1.421413741f +
               t * (-1.453152027f + t * 1.061405429f))));
  float e = __expf(-z * z);
  float erf_abs = fmaf(-poly, e, 1.0f);
  float erfv = copysignf(erf_abs, x);
  return 0.5f * x * (1.0f + erfv);
}

__device__ __forceinline__ void gload_lds16(const void* g, void* l){
  __builtin_amdgcn_global_load_lds(
      (const __attribute__((address_space(1))) u32*)g,
      (__attribute__((address_space(3))) u32*)l, 16, 0, 0);
}

// ---------------- weight transpose: [E][R][C] fp32 -> [E][C][R] bf16 ----------

__global__ __launch_bounds__(256) void transpose_convert_kernel(
    const float* __restrict__ in, unsigned short* __restrict__ out,
    int R, int C){
  __shared__ float tile[64][65];
  const int e  = blockIdx.z;
  const int c0 = blockIdx.x * 64;
  const int r0 = blockIdx.y * 64;
  const int tid = threadIdx.x;
  const size_t base = (size_t)e * R * C;
  {
    const int r  = tid >> 4;          // 0..15
    const int c4 = (tid & 15) * 4;    // 0..60
    #pragma unroll
    for (int it = 0; it < 4; it++){
      int rr = r + it * 16;
      float4 v = *(const float4*)(in + base + (size_t)(r0 + rr) * C + c0 + c4);
      tile[rr][c4 + 0] = v.x;
      tile[rr][c4 + 1] = v.y;
      tile[rr][c4 + 2] = v.z;
      tile[rr][c4 + 3] = v.w;
    }
  }
  __syncthreads();
  {
    const int c  = tid >> 4;          // 0..15
    const int r4 = (tid & 15) * 4;
    #pragma unroll
    for (int it = 0; it < 4; it++){
      int cc = c + it * 16;
      ushort4 w;
      w.x = f2bf(tile[r4 + 0][cc]);
      w.y = f2bf(tile[r4 + 1][cc]);
      w.z = f2bf(tile[r4 + 2][cc]);
      w.w = f2bf(tile[r4 + 3][cc]);
      *(ushort4*)(out + base + (size_t)(c0 + cc) * R + r0 + r4) = w;
    }
  }
}

// ---------------- router (also converts x -> bf16, single pass) --------------

__global__ __launch_bounds__(64) void router_kernel(
    const float* __restrict__ x,
    const float* __restrict__ Wr,
    const float* __restrict__ br,
    int* __restrict__ counts,
    int* __restrict__ topk_idx,
    float* __restrict__ topk_gate,
    unsigned short* __restrict__ xb){
  const int n = blockIdx.x;
  const int lane = threadIdx.x;      // 64 threads
  const float* xr = x + (size_t)n * D_MODEL;
  unsigned short* xbr = xb + (size_t)n * D_MODEL;
  float acc[N_EXPERTS];
  #pragma unroll
  for (int e = 0; e < N_EXPERTS; e++) acc[e] = 0.f;
  #pragma unroll
  for (int it = 0; it < 4; it++){
    int d = it * 256 + lane * 4;
    float4 v = *(const float4*)(xr + d);
    ushort4 w;
    w.x = f2bf(v.x); w.y = f2bf(v.y); w.z = f2bf(v.z); w.w = f2bf(v.w);
    *(ushort4*)(xbr + d) = w;
    const float* wr = Wr + (size_t)d * N_EXPERTS;
    const float* vv = &v.x;
    #pragma unroll
    for (int j = 0; j < 4; j++)
      #pragma unroll
      for (int e = 0; e < N_EXPERTS; e++)
        acc[e] = fmaf(vv[j], wr[j * N_EXPERTS + e], acc[e]);
  }
  #pragma unroll
  for (int e = 0; e < N_EXPERTS; e++){
    float v = acc[e];
    for (int o = 32; o > 0; o >>= 1) v += __shfl_xor(v, o, 64);
    acc[e] = v;
  }
  if (lane == 0){
    float logits[N_EXPERTS];
    float m = -1e30f;
    #pragma unroll
    for (int e = 0; e < N_EXPERTS; e++){
      logits[e] = acc[e] + br[e];
      m = fmaxf(m, logits[e]);
    }
    float p[N_EXPERTS]; float Z = 0.f;
    #pragma unroll
    for (int e = 0; e < N_EXPERTS; e++){ p[e] = expf(logits[e] - m); Z += p[e]; }
    #pragma unroll
    for (int e = 0; e < N_EXPERTS; e++) p[e] /= Z;
    int i0 = 0;
    #pragma unroll
    for (int e = 1; e < N_EXPERTS; e++) if (p[e] > p[i0]) i0 = e;
    int i1 = (i0 == 0) ? 1 : 0;
    #pragma unroll
    for (int e = 0; e < N_EXPERTS; e++){
      if (e == i0) continue;
      if (p[e] > p[i1]) i1 = e;
    }
    float s = p[i0] + p[i1] + 1e-9f;
    topk_idx[n * 2 + 0] = i0;
    topk_idx[n * 2 + 1] = i1;
    topk_gate[n * 2 + 0] = p[i0] / s;
    topk_gate[n * 2 + 1] = p[i1] / s;
    atomicAdd(&counts[i0], 1);
    atomicAdd(&counts[i1], 1);
  }
}

// ---------------- bookkeeping: offsets + tile table, parallel ----------------

__global__ __launch_bounds__(256) void prefix_kernel(
    const int* __restrict__ counts,
    int* __restrict__ offsets,
    int* __restrict__ cursor,
    int* __restrict__ tile_e,
    int* __restrict__ tile_m){
  __shared__ int scnt[N_EXPERTS];
  __shared__ int soff[N_EXPERTS];
  const int tid = threadIdx.x;
  if (tid < N_EXPERTS) scnt[tid] = counts[tid];
  __syncthreads();
  if (tid == 0){
    int o = 0;
    for (int e = 0; e < N_EXPERTS; e++){ soff[e] = o; o += scnt[e]; }
  }
  __syncthreads();
  if (tid < N_EXPERTS){ offsets[tid] = soff[tid]; cursor[tid] = soff[tid]; }
  if (tid < MAXTILES){
    int t = tid, te = -1, tm = 0, acc = 0;
    #pragma unroll
    for (int e = 0; e < N_EXPERTS; e++){
      int nt = (scnt[e] + BM - 1) / BM;
      if (te < 0 && t < acc + nt){ te = e; tm = t - acc; }
      acc += nt;
    }
    tile_e[tid] = te; tile_m[tid] = tm;
  }
}

__global__ void assign_kernel(const int* __restrict__ topk_idx,
                              const float* __restrict__ topk_gate,
                              int* __restrict__ cursor,
                              int* __restrict__ bucket_token,
                              float* __restrict__ bucket_gate,
                              int* __restrict__ slot_of){
  int n = blockIdx.x * blockDim.x + threadIdx.x;
  if (n >= NTOK) return;
  #pragma unroll
  for (int k = 0; k < TOPK_; k++){
    int e = topk_idx[n * 2 + k];
    float g = topk_gate[n * 2 + k];
    int s = atomicAdd(&cursor[e], 1);
    bucket_token[s] = n;
    bucket_gate[s] = g;
    slot_of[n * 2 + k] = s;
  }
}

// ---------------- grouped GEMM, 256^2 tile, m201-style 8-phase schedule ------
//
// 4 phases per K-tile u (Gray quadrant order), each phase:
//   {ds_reads ; stage 1 half-tile (2 gloads)} ; s_barrier ;
//   lgkmcnt(0)+sched_barrier(0) ; setprio(1) ; 16 MFMA ; setprio(0) ;
//   sched_barrier(0) ; [counted vmcnt] ; s_barrier
// sched_barrier(0) pins the MFMA cluster inside its phase (hipcc otherwise
// hoists/sinks register-only MFMAs across inline-asm waits — rule #18; this
// was the rounds-1/2 failure: two different intended schedules, identical
// emitted behavior, identical 22% MfmaUtil).
//
// Quadrants: ph1:(A0,B0) ph2:(A0,B1) ph3:(A1,B1) ph4:(A1,B0).
// Stage order per tile u: ph1:B0(u+1) ph2:A1(u+1) [other buffer, always safe]
//                         ph3:A0(u+2) ph4:B1(u+2) [current buffer; region's
//                         last read completed >=1 barrier-pair earlier].
// Waits: end-ph2 vmcnt(8) lands A1(u) [staged ph2(u-1), 4-phase lead];
//        end-ph4 vmcnt(6) lands {A0,B1,B0}(u+1) [>=3-phase leads].
// In-flight oscillates 6..10 loads; never vmcnt(0) in the main loop.

#define BARR do { asm volatile("" ::: "memory"); \
                  __builtin_amdgcn_s_barrier(); \
                  asm volatile("" ::: "memory"); } while(0)
#define VMW(n) asm volatile("s_waitcnt vmcnt(" #n ")" ::: "memory")
#define LGKM0 do { asm volatile("s_waitcnt lgkmcnt(0)" ::: "memory"); \
                   __builtin_amdgcn_sched_barrier(0); } while(0)

// stage A half-tile (half=0: rows 0-127, half=1: rows 128-255) at k offset
#define SA_(bufi, half, k) do { \
  gload_lds16(asrc[2*(half)]   + (k), &As[bufi][(2*(half))*64   + (tid>>3)][(tid&7)*8]); \
  gload_lds16(asrc[2*(half)+1] + (k), &As[bufi][(2*(half)+1)*64 + (tid>>3)][(tid&7)*8]); \
} while(0)
#define SB_(bufi, half, k) do { \
  gload_lds16(bsrc[2*(half)]   + (k), &Bs[bufi][(2*(half))*64   + (tid>>3)][(tid&7)*8]); \
  gload_lds16(bsrc[2*(half)+1] + (k), &Bs[bufi][(2*(half)+1)*64 + (tid>>3)][(tid&7)*8]); \
} while(0)

// load A fragments for A-half qm (4 M-frags x 2 k-slices = 8 ds_read_b128)
#define LDA_(bc, qm) do { \
  _Pragma("unroll") \
  for (int i_ = 0; i_ < 4; i_++){ \
    const int r_ = (qm)*128 + rw*64 + i_*16 + fm; \
    a[i_][0] = *(const bf16x8*)&As[bc][r_][ck0]; \
    a[i_][1] = *(const bf16x8*)&As[bc][r_][ck1]; \
  } \
} while(0)
// load B fragments for B-half qn (2 N-frags x 2 k-slices = 4 ds_read_b128)
#define LDB_(bc, qn) do { \
  _Pragma("unroll") \
  for (int j_ = 0; j_ < 2; j_++){ \
    const int r_ = (qn)*128 + cw*32 + j_*16 + fm; \
    b[j_][0] = *(const bf16x8*)&Bs[bc][r_][ck0]; \
    b[j_][1] = *(const bf16x8*)&Bs[bc][r_][ck1]; \
  } \
} while(0)

#define MFQ(qm, qn) do { \
  __builtin_amdgcn_s_setprio(1); \
  _Pragma("unroll") \
  for (int i_ = 0; i_ < 4; i_++) \
    _Pragma("unroll") \
    for (int j_ = 0; j_ < 2; j_++){ \
      acc[qm][qn][i_][j_] = __builtin_amdgcn_mfma_f32_16x16x32_bf16(a[i_][0], b[j_][0], acc[qm][qn][i_][j_], 0, 0, 0); \
      acc[qm][qn][i_][j_] = __builtin_amdgcn_mfma_f32_16x16x32_bf16(a[i_][1], b[j_][1], acc[qm][qn][i_][j_], 0, 0, 0); \
    } \
  __builtin_amdgcn_s_setprio(0); \
  __builtin_amdgcn_sched_barrier(0); \
} while(0)

// steady-state tile: compute buf bc, stage per ledger (kc = this tile's k)
#define TILE8(bc, kc) do { \
  LDA_(bc,0); LDB_(bc,0); SB_(1-(bc), 0, (kc)+BK);   BARR; LGKM0; MFQ(0,0);          BARR; \
  LDB_(bc,1);             SA_(1-(bc), 1, (kc)+BK);   BARR; LGKM0; MFQ(0,1); VMW(8);  BARR; \
  LDA_(bc,1);             SA_((bc),   0, (kc)+2*BK); BARR; LGKM0; MFQ(1,1);          BARR; \
  LDB_(bc,0);             SB_((bc),   1, (kc)+2*BK); BARR; LGKM0; MFQ(1,0); VMW(6);  BARR; \
} while(0)

// tile NT-2: stages only B0,A1 of tile NT-1
#define TILE_PRE(bc, kc) do { \
  LDA_(bc,0); LDB_(bc,0); SB_(1-(bc), 0, (kc)+BK);   BARR; LGKM0; MFQ(0,0);          BARR; \
  LDB_(bc,1);             SA_(1-(bc), 1, (kc)+BK);   BARR; LGKM0; MFQ(0,1); VMW(8);  BARR; \
  LDA_(bc,1);                                        BARR; LGKM0; MFQ(1,1);          BARR; \
  LDB_(bc,0);                                        BARR; LGKM0; MFQ(1,0); VMW(2);  BARR; \
} while(0)

// tile NT-1: no stages
#define TILE_LAST(bc) do { \
  LDA_(bc,0); LDB_(bc,0);                            BARR; LGKM0; MFQ(0,0);          BARR; \
  LDB_(bc,1);                                        BARR; LGKM0; MFQ(0,1); VMW(0);  BARR; \
  LDA_(bc,1);                                        BARR; LGKM0; MFQ(1,1);          BARR; \
  LDB_(bc,0);                                        BARR; LGKM0; MFQ(1,0); \
} while(0)

// MODE 0: gemm1  h = gelu(xb[token] @ W1t + b1)     (KDIM=1024, NDIM=4096)
// MODE 1: gemm2  y = g * (hb[slot] @ W2t + b2)      (KDIM=4096, NDIM=1024)
template<int KDIM, int NDIM, int MODE>
__global__ __launch_bounds__(512, 2) void moe_gemm_kernel(
    const unsigned short* __restrict__ A,
    const unsigned short* __restrict__ Wt,
    const float* __restrict__ bias_g,
    const int* __restrict__ bucket_token,
    const float* __restrict__ bucket_gate,
    const int* __restrict__ offsets,
    const int* __restrict__ counts,
    const int* __restrict__ tile_e,
    const int* __restrict__ tile_m,
    unsigned short* __restrict__ out){
  const int e = tile_e[blockIdx.y];
  if (e < 0) return;
  const int mtile = tile_m[blockIdx.y];
  const int ntile = blockIdx.x;
  const int count = counts[e];
  const int off = offsets[e];

  __shared__ unsigned short As[2][BM][BK];   // 64 KB
  __shared__ unsigned short Bs[2][BN][BK];   // 64 KB

  const int tid  = threadIdx.x;
  const int lane = tid & 63;
  const int wave = tid >> 6;          // 8 waves: 2 (row) x 4 (col)
  const int rw = wave >> 2;           // 0..1: 64-row block within A-half
  const int cw = wave & 3;            // 0..3: 32-col block within B-half
  const int fm = lane & 15;
  // swizzled k-column element offsets for the two k-subtiles (kk=0,32)
  const int ck0 = (((lane >> 4)    ) ^ (lane & 7)) * 8;
  const int ck1 = (((lane >> 4) + 4) ^ (lane & 7)) * 8;
  // staging: thread covers row (c*64 + tid>>3), LDS colgrp tid&7,
  // global colgrp (tid&7)^((tid>>3)&7)  [LDS[r][c] = global[r][c ^ (r&7)]]
  const int cg = ((tid & 7) ^ ((tid >> 3) & 7)) * 8;

  const unsigned short* asrc[4];
  const unsigned short* bsrc[4];
  #pragma unroll
  for (int c = 0; c < 4; c++){
    int m = mtile * BM + c * 64 + (tid >> 3);
    int mm = min(m, count - 1);
    size_t arow = (MODE == 0) ? (size_t)bucket_token[off + mm] : (size_t)(off + mm);
    asrc[c] = A + arow * KDIM + cg;
    bsrc[c] = Wt + ((size_t)e * NDIM + (size_t)ntile * BN + c * 64 + (tid >> 3)) * KDIM + cg;
  }

  const f32x4 zero = {0.f, 0.f, 0.f, 0.f};
  f32x4 acc[2][2][4][2];
  #pragma unroll
  for (int qm = 0; qm < 2; qm++)
    #pragma unroll
    for (int qn = 0; qn < 2; qn++)
      #pragma unroll
      for (int i = 0; i < 4; i++)
        #pragma unroll
        for (int j = 0; j < 2; j++) acc[qm][qn][i][j] = zero;

  bf16x8 a[4][2], b[2][2];

  // ---- prologue: stage in steady-state FIFO order ----
  // A0(0),B1(0) [~ph3,4(-2)]; B0(0),A1(0) [~ph1,2(-1)]; A0(1),B1(1) [~ph3,4(-1)]
  SA_(0,0,0); SB_(0,1,0);
  SB_(0,0,0); SA_(0,1,0);
  SA_(1,0,BK); SB_(1,1,BK);
  VMW(6); BARR;   // lands A0(0),B1(0),B0(0); leaves {A1(0),A0(1),B1(1)}

  // main loop: tiles 0..NT-3 in buf-alternating pairs (NT even)
  int k = 0;
  #pragma unroll 1
  for (int tp = 0; tp < (KDIM/BK - 2) / 2; ++tp){
    TILE8(0, k);
    TILE8(1, k + BK);
    k += 2*BK;
  }
  TILE_PRE(0, k);
  TILE_LAST(1);

  // ---- epilogue ----
  const float* bias = bias_g + (size_t)e * NDIM + (size_t)ntile * BN;
  float bj[2][2];
  #pragma unroll
  for (int qn = 0; qn < 2; qn++)
    #pragma unroll
    for (int j = 0; j < 2; j++)
      bj[qn][j] = bias[qn*128 + cw*32 + j*16 + fm];

  #pragma unroll
  for (int qm = 0; qm < 2; qm++){
    #pragma unroll
    for (int i = 0; i < 4; i++){
      #pragma unroll
      for (int r = 0; r < 4; r++){
        int mrel = qm*128 + rw*64 + i*16 + (lane >> 4) * 4 + r;
        int m = mtile * BM + mrel;
        if (m >= count) continue;
        int slot = off + m;
        unsigned short* orow = out + (size_t)slot * NDIM + (size_t)ntile * BN;
        if constexpr (MODE == 0){
          #pragma unroll
          for (int qn = 0; qn < 2; qn++)
            #pragma unroll
            for (int j = 0; j < 2; j++){
              float v = acc[qm][qn][i][j][r] + bj[qn][j];
              orow[qn*128 + cw*32 + j*16 + fm] = f2bf(gelu_fast(v));
            }
        } else {
          float g = bucket_gate[slot];
          #pragma unroll
          for (int qn = 0; qn < 2; qn++)
            #pragma unroll
            for (int j = 0; j < 2; j++){
              float v = g * (acc[qm][qn][i][j][r] + bj[qn][j]);
              orow[qn*128 + cw*32 + j*16 + fm] = f2bf(v);
            }
        }
      }
    }
  }
}

// ---------------- combine: out[t] = y[slot0(t)] + y[slot1(t)] ----------------

__global__ __launch_bounds__(256) void combine_kernel(
    const unsigned short* __restrict__ y,
    const int* __restrict__ slot_of,
    float* __restrict__ out){
  const int t = blockIdx.x;
  const int d = threadIdx.x * 4;
  const int s0 = slot_of[t * 2 + 0];
  const int s1 = slot_of[t * 2 + 1];
  uint2 a = *(const uint2*)(y + (size_t)s0 * D_MODEL + d);
  uint2 b = *(const uint2*)(y + (size_t)s1 * D_MODEL + d);
  float4 r;
  r.x = bf2f((unsigned short)(a.x & 0xffff)) + bf2f((unsigned short)(b.x & 0xffff));
  r.y = bf2f((unsigned short)(a.x >> 16))    + bf2f((unsigned short)(b.x >> 16));
  r.z = bf2f((unsigned short)(a.y & 0xffff)) + bf2f((unsigned short)(b.y & 0xffff));
  r.w = bf2f((unsigned short)(a.y >> 16))    + bf2f((unsigned short)(b.y >> 16));
  *(float4*)(out + (size_t)t * D_MODEL + d) = r;
}

// ---------------- launch ----------------

extern "C" void kernel_launch(void* const* d_in, const int* in_sizes, int n_in,
                              void* d_out, int out_size, void* d_ws, size_t ws_size,
                              hipStream_t stream) {
  (void)in_sizes; (void)n_in; (void)ws_size; (void)out_size;
  const float* x  = (const float*)d_in[0];
  const float* Wr = (const float*)d_in[1];
  const float* br = (const float*)d_in[2];
  const float* W1 = (const float*)d_in[3];
  const float* b1 = (const float*)d_in[4];
  const float* W2 = (const float*)d_in[5];
  const float* b2 = (const float*)d_in[6];
  float* out = (float*)d_out;

  char* ws = (char*)d_ws;
  size_t p = 0;
  auto alloc = [&](size_t bytes) -> void* {
    void* r = ws + p;
    p = (p + bytes + 255) & ~(size_t)255;
    return r;
  };

  int*   counts       = (int*)  alloc(N_EXPERTS * sizeof(int));
  int*   offsets      = (int*)  alloc(N_EXPERTS * sizeof(int));
  int*   cursor       = (int*)  alloc(N_EXPERTS * sizeof(int));
  int*   tile_e       = (int*)  alloc(MAXTILES * sizeof(int));
  int*   tile_m       = (int*)  alloc(MAXTILES * sizeof(int));
  int*   topk_idx     = (int*)  alloc((size_t)NTOK * 2 * sizeof(int));
  float* topk_gate    = (float*)alloc((size_t)NTOK * 2 * sizeof(float));
  int*   bucket_token = (int*)  alloc((size_t)NSLOT * sizeof(int));
  float* bucket_gate  = (float*)alloc((size_t)NSLOT * sizeof(float));
  int*   slot_of      = (int*)  alloc((size_t)NTOK * 2 * sizeof(int));
  unsigned short* xb  = (unsigned short*)alloc((size_t)NTOK * D_MODEL * 2);
  unsigned short* W1t = (unsigned short*)alloc((size_t)N_EXPERTS * D_MODEL * D_FF * 2);
  unsigned short* W2t = (unsigned short*)alloc((size_t)N_EXPERTS * D_MODEL * D_FF * 2);
  unsigned short* hb  = (unsigned short*)alloc((size_t)NSLOT * D_FF * 2);
  // y (bf16, 32 MB) aliases W1t (64 MB): W1t is dead once gemm1 completes.
  unsigned short* y = W1t;

  hipMemsetAsync(counts, 0, N_EXPERTS * sizeof(int), stream);

  // Transposes FIRST so nothing streams between gemm1 and gemm2 (keeps h
  // L3-resident for gemm2), and gemm1 reads recently-written xb/W1t.
  transpose_convert_kernel<<<dim3(D_MODEL / 64, D_FF / 64, N_EXPERTS), 256, 0, stream>>>(
      W2, W2t, D_FF, D_MODEL);
  transpose_convert_kernel<<<dim3(D_FF / 64, D_MODEL / 64, N_EXPERTS), 256, 0, stream>>>(
      W1, W1t, D_MODEL, D_FF);
  router_kernel<<<NTOK, 64, 0, stream>>>(x, Wr, br, counts, topk_idx, topk_gate, xb);
  prefix_kernel<<<1, 256, 0, stream>>>(counts, offsets, cursor, tile_e, tile_m);
  assign_kernel<<<NTOK / 256, 256, 0, stream>>>(topk_idx, topk_gate, cursor,
                                                bucket_token, bucket_gate, slot_of);
  moe_gemm_kernel<D_MODEL, D_FF, 0><<<dim3(D_FF / BN, MAXTILES), 512, 0, stream>>>(
      xb, W1t, b1, bucket_token, nullptr, offsets, counts, tile_e, tile_m, hb);
  moe_gemm_kernel<D_FF, D_MODEL, 1><<<dim3(D_MODEL / BN, MAXTILES), 512, 0, stream>>>(
      hb, W2t, b2, nullptr, bucket_gate, offsets, counts, tile_e, tile_m, y);
  combine_kernel<<<NTOK, 256, 0, stream>>>(y, slot_of, out);
}

// Round 4
// 1005.430 us; speedup vs baseline: 1.0263x; 1.0109x over previous
//
#include <hip/hip_runtime.h>
#include <cstdint>
#include <cstddef>

#define D_MODEL 1024
#define D_FF    4096
#define N_EXPERTS 8
#define TOPK_    2
#define NTOK    8192
#define NSLOT   (NTOK*TOPK_)
#define MAXTILES 136

#define BM 128
#define BN 128
#define BK 64

typedef __attribute__((ext_vector_type(8))) short bf16x8;
typedef __attribute__((ext_vector_type(4))) float f32x4;
typedef unsigned int u32;

__device__ __forceinline__ unsigned short f2bf(float f){
  union { float f; u32 u; } v; v.f = f;
  u32 u = v.u;
  u32 r = (u + 0x7FFFu + ((u >> 16) & 1u)) >> 16;
  return (unsigned short)r;
}

__device__ __forceinline__ float bf2f(unsigned short s){
  union { u32 u; float f; } v; v.u = (u32)s << 16; return v.f;
}

// gelu via Abramowitz-Stegun 7.1.26 erf, |err| <= 1.5e-7 abs.
__device__ __forceinline__ float gelu_fast(float x){
  float z = fabsf(x) * 0.70710678118654752f;
  float t = __builtin_amdgcn_rcpf(fmaf(0.3275911f, z, 1.0f));
  float poly = t * (0.254829592f + t * (-0.284496736f + t * (1.421413741f +
               t * (-1.453152027f + t * 1.061405429f))));
  float e = __expf(-z * z);
  float erf_abs = fmaf(-poly, e, 1.0f);
  float erfv = copysignf(erf_abs, x);
  return 0.5f * x * (1.0f + erfv);
}

__device__ __forceinline__ void gload_lds16(const void* g, void* l){
  __builtin_amdgcn_global_load_lds(
      (const __attribute__((address_space(1))) u32*)g,
      (__attribute__((address_space(3))) u32*)l, 16, 0, 0);
}

// ---------------- weight transpose: [E][R][C] fp32 -> [E][C][R] bf16 ----------
// 64x64 tiles; float4 global reads, ushort4 global writes (8 B/lane both ways).

__global__ __launch_bounds__(256) void transpose_convert_kernel(
    const float* __restrict__ in, unsigned short* __restrict__ out,
    int R, int C){
  __shared__ float tile[64][65];
  const int e  = blockIdx.z;
  const int c0 = blockIdx.x * 64;
  const int r0 = blockIdx.y * 64;
  const int tid = threadIdx.x;
  const size_t base = (size_t)e * R * C;
  {
    const int r  = tid >> 4;          // 0..15
    const int c4 = (tid & 15) * 4;    // 0..60
    #pragma unroll
    for (int it = 0; it < 4; it++){
      int rr = r + it * 16;
      float4 v = *(const float4*)(in + base + (size_t)(r0 + rr) * C + c0 + c4);
      tile[rr][c4 + 0] = v.x;
      tile[rr][c4 + 1] = v.y;
      tile[rr][c4 + 2] = v.z;
      tile[rr][c4 + 3] = v.w;
    }
  }
  __syncthreads();
  {
    const int c  = tid >> 4;          // 0..15
    const int r4 = (tid & 15) * 4;
    #pragma unroll
    for (int it = 0; it < 4; it++){
      int cc = c + it * 16;
      ushort4 w;
      w.x = f2bf(tile[r4 + 0][cc]);
      w.y = f2bf(tile[r4 + 1][cc]);
      w.z = f2bf(tile[r4 + 2][cc]);
      w.w = f2bf(tile[r4 + 3][cc]);
      *(ushort4*)(out + base + (size_t)(c0 + cc) * R + r0 + r4) = w;
    }
  }
}

// ---------------- router (also converts x -> bf16, single pass) --------------
// 256 threads = 4 waves, one token per wave.

__global__ __launch_bounds__(256) void router_kernel(
    const float* __restrict__ x,
    const float* __restrict__ Wr,
    const float* __restrict__ br,
    int* __restrict__ counts,
    int* __restrict__ topk_idx,
    float* __restrict__ topk_gate,
    unsigned short* __restrict__ xb){
  const int n = blockIdx.x * 4 + (threadIdx.x >> 6);
  const int lane = threadIdx.x & 63;
  const float* xr = x + (size_t)n * D_MODEL;
  unsigned short* xbr = xb + (size_t)n * D_MODEL;
  float acc[N_EXPERTS];
  #pragma unroll
  for (int e = 0; e < N_EXPERTS; e++) acc[e] = 0.f;
  #pragma unroll
  for (int it = 0; it < 4; it++){
    int d = it * 256 + lane * 4;
    float4 v = *(const float4*)(xr + d);
    ushort4 w;
    w.x = f2bf(v.x); w.y = f2bf(v.y); w.z = f2bf(v.z); w.w = f2bf(v.w);
    *(ushort4*)(xbr + d) = w;
    const float* wr = Wr + (size_t)d * N_EXPERTS;
    const float* vv = &v.x;
    #pragma unroll
    for (int j = 0; j < 4; j++)
      #pragma unroll
      for (int e = 0; e < N_EXPERTS; e++)
        acc[e] = fmaf(vv[j], wr[j * N_EXPERTS + e], acc[e]);
  }
  #pragma unroll
  for (int e = 0; e < N_EXPERTS; e++){
    float v = acc[e];
    for (int o = 32; o > 0; o >>= 1) v += __shfl_xor(v, o, 64);
    acc[e] = v;
  }
  if (lane == 0){
    float logits[N_EXPERTS];
    float m = -1e30f;
    #pragma unroll
    for (int e = 0; e < N_EXPERTS; e++){
      logits[e] = acc[e] + br[e];
      m = fmaxf(m, logits[e]);
    }
    float p[N_EXPERTS]; float Z = 0.f;
    #pragma unroll
    for (int e = 0; e < N_EXPERTS; e++){ p[e] = expf(logits[e] - m); Z += p[e]; }
    #pragma unroll
    for (int e = 0; e < N_EXPERTS; e++) p[e] /= Z;
    int i0 = 0;
    #pragma unroll
    for (int e = 1; e < N_EXPERTS; e++) if (p[e] > p[i0]) i0 = e;
    int i1 = (i0 == 0) ? 1 : 0;
    #pragma unroll
    for (int e = 0; e < N_EXPERTS; e++){
      if (e == i0) continue;
      if (p[e] > p[i1]) i1 = e;
    }
    float s = p[i0] + p[i1] + 1e-9f;
    topk_idx[n * 2 + 0] = i0;
    topk_idx[n * 2 + 1] = i1;
    topk_gate[n * 2 + 0] = p[i0] / s;
    topk_gate[n * 2 + 1] = p[i1] / s;
    atomicAdd(&counts[i0], 1);
    atomicAdd(&counts[i1], 1);
  }
}

// ---------------- bookkeeping: offsets + tile table, parallel ----------------

__global__ __launch_bounds__(256) void prefix_kernel(
    const int* __restrict__ counts,
    int* __restrict__ offsets,
    int* __restrict__ cursor,
    int* __restrict__ tile_e,
    int* __restrict__ tile_m){
  __shared__ int scnt[N_EXPERTS];
  __shared__ int soff[N_EXPERTS];
  const int tid = threadIdx.x;
  if (tid < N_EXPERTS) scnt[tid] = counts[tid];
  __syncthreads();
  if (tid == 0){
    int o = 0;
    for (int e = 0; e < N_EXPERTS; e++){ soff[e] = o; o += scnt[e]; }
  }
  __syncthreads();
  if (tid < N_EXPERTS){ offsets[tid] = soff[tid]; cursor[tid] = soff[tid]; }
  if (tid < MAXTILES){
    int t = tid, te = -1, tm = 0, acc = 0;
    #pragma unroll
    for (int e = 0; e < N_EXPERTS; e++){
      int nt = (scnt[e] + BM - 1) / BM;
      if (te < 0 && t < acc + nt){ te = e; tm = t - acc; }
      acc += nt;
    }
    tile_e[tid] = te; tile_m[tid] = tm;
  }
}

__global__ void assign_kernel(const int* __restrict__ topk_idx,
                              const float* __restrict__ topk_gate,
                              int* __restrict__ cursor,
                              int* __restrict__ bucket_token,
                              float* __restrict__ bucket_gate){
  int n = blockIdx.x * blockDim.x + threadIdx.x;
  if (n >= NTOK) return;
  #pragma unroll
  for (int k = 0; k < TOPK_; k++){
    int e = topk_idx[n * 2 + k];
    float g = topk_gate[n * 2 + k];
    int s = atomicAdd(&cursor[e], 1);
    bucket_token[s] = n;
    bucket_gate[s] = g;
  }
}

// ---------------- grouped GEMM 1: h = gelu(x @ W1 + b1) ----------------
// Round-0 verified structure + XCD-chunked block swizzle (grid 32x136, %8==0).

__global__ __launch_bounds__(256, 3) void gemm1_kernel(
    const unsigned short* __restrict__ xb,
    const unsigned short* __restrict__ W1t,
    const float* __restrict__ b1,
    const int* __restrict__ bucket_token,
    const int* __restrict__ offsets,
    const int* __restrict__ counts,
    const int* __restrict__ tile_e,
    const int* __restrict__ tile_m,
    unsigned short* __restrict__ h){
  // XCD swizzle: each XCD gets 544 contiguous logical blocks = 17 mtiles x 32 ntiles.
  int f = blockIdx.y * 32 + blockIdx.x;
  f = (f & 7) * ((32 * MAXTILES) >> 3) + (f >> 3);
  const int e = tile_e[f / 32];
  if (e < 0) return;
  const int mtile = tile_m[f / 32];
  const int ntile = f % 32;
  const int count = counts[e];
  const int off = offsets[e];

  __shared__ unsigned short As[BM][BK];
  __shared__ unsigned short Bs[BN][BK];

  const int tid  = threadIdx.x;
  const int lane = tid & 63;
  const int wave = tid >> 6;

  const int srow   = wave * 8 + (lane >> 3);
  const int scol_l = (lane & 7) * 8;
  const int scol_g = (((lane & 7) ^ (lane >> 3)) * 8);

  int arow[4];
  #pragma unroll
  for (int j = 0; j < 4; j++){
    int m = mtile * BM + j * 32 + srow;
    arow[j] = bucket_token[off + min(m, count - 1)];
  }
  const unsigned short* Bbase = W1t + ((size_t)e * D_FF + (size_t)ntile * BN) * D_MODEL;

  const f32x4 zero = {0.f, 0.f, 0.f, 0.f};
  f32x4 acc[4][4];
  #pragma unroll
  for (int i = 0; i < 4; i++)
    #pragma unroll
    for (int j = 0; j < 4; j++) acc[i][j] = zero;

  const int wm = (wave >> 1) * 64;
  const int wn = (wave & 1) * 64;
  const int frag_m = lane & 15;

  for (int k0 = 0; k0 < D_MODEL; k0 += BK){
    __syncthreads();
    #pragma unroll
    for (int j = 0; j < 4; j++)
      gload_lds16(xb + (size_t)arow[j] * D_MODEL + k0 + scol_g, &As[j * 32 + srow][scol_l]);
    #pragma unroll
    for (int j = 0; j < 4; j++)
      gload_lds16(Bbase + (size_t)(j * 32 + srow) * D_MODEL + k0 + scol_g, &Bs[j * 32 + srow][scol_l]);
    __syncthreads();
    #pragma unroll
    for (int kk = 0; kk < BK; kk += 32){
      const int ck = ((((kk >> 3) + (lane >> 4)) ^ (lane & 7)) * 8);
      bf16x8 a[4], b[4];
      #pragma unroll
      for (int i = 0; i < 4; i++)
        a[i] = *(const bf16x8*)&As[wm + i * 16 + frag_m][ck];
      #pragma unroll
      for (int j = 0; j < 4; j++)
        b[j] = *(const bf16x8*)&Bs[wn + j * 16 + frag_m][ck];
      #pragma unroll
      for (int i = 0; i < 4; i++)
        #pragma unroll
        for (int j = 0; j < 4; j++)
          acc[i][j] = __builtin_amdgcn_mfma_f32_16x16x32_bf16(a[i], b[j], acc[i][j], 0, 0, 0);
    }
  }

  const float* bias = b1 + (size_t)e * D_FF + (size_t)ntile * BN;
  #pragma unroll
  for (int i = 0; i < 4; i++){
    #pragma unroll
    for (int r = 0; r < 4; r++){
      int mrel = wm + i * 16 + (lane >> 4) * 4 + r;
      int m = mtile * BM + mrel;
      if (m >= count) continue;
      size_t hrow = (size_t)(off + m) * D_FF + (size_t)ntile * BN;
      #pragma unroll
      for (int j = 0; j < 4; j++){
        int nrel = wn + j * 16 + (lane & 15);
        float v = acc[i][j][r] + bias[nrel];
        h[hrow + nrel] = f2bf(gelu_fast(v));
      }
    }
  }
}

// ---------------- grouped GEMM 2 + fused combine ----------------
// y-buffer eliminated: epilogue does fp32 atomicAdd of g*(h@W2+b2) directly
// into out[token] (pre-zeroed). Each token receives exactly TOPK_=2 adds.

__global__ __launch_bounds__(256, 3) void gemm2_kernel(
    const unsigned short* __restrict__ h,
    const unsigned short* __restrict__ W2t,   // [E][1024][4096]
    const float* __restrict__ b2,
    const float* __restrict__ bucket_gate,
    const int* __restrict__ bucket_token,
    const int* __restrict__ offsets,
    const int* __restrict__ counts,
    const int* __restrict__ tile_e,
    const int* __restrict__ tile_m,
    float* __restrict__ out){
  // XCD swizzle: grid 8x136 = 1088 (%8==0), 136 logical blocks per XCD.
  int f = blockIdx.y * 8 + blockIdx.x;
  f = (f & 7) * ((8 * MAXTILES) >> 3) + (f >> 3);
  const int e = tile_e[f / 8];
  if (e < 0) return;
  const int mtile = tile_m[f / 8];
  const int ntile = f % 8;
  const int count = counts[e];
  const int off = offsets[e];

  __shared__ unsigned short As[BM][BK];
  __shared__ unsigned short Bs[BN][BK];

  const int tid  = threadIdx.x;
  const int lane = tid & 63;
  const int wave = tid >> 6;

  const int srow   = wave * 8 + (lane >> 3);
  const int scol_l = (lane & 7) * 8;
  const int scol_g = (((lane & 7) ^ (lane >> 3)) * 8);

  size_t aslot[4];
  #pragma unroll
  for (int j = 0; j < 4; j++){
    int m = mtile * BM + j * 32 + srow;
    aslot[j] = (size_t)(off + min(m, count - 1));
  }
  const unsigned short* Bbase = W2t + ((size_t)e * D_MODEL + (size_t)ntile * BN) * D_FF;

  const f32x4 zero = {0.f, 0.f, 0.f, 0.f};
  f32x4 acc[4][4];
  #pragma unroll
  for (int i = 0; i < 4; i++)
    #pragma unroll
    for (int j = 0; j < 4; j++) acc[i][j] = zero;

  const int wm = (wave >> 1) * 64;
  const int wn = (wave & 1) * 64;
  const int frag_m = lane & 15;

  for (int k0 = 0; k0 < D_FF; k0 += BK){
    __syncthreads();
    #pragma unroll
    for (int j = 0; j < 4; j++)
      gload_lds16(h + aslot[j] * D_FF + k0 + scol_g, &As[j * 32 + srow][scol_l]);
    #pragma unroll
    for (int j = 0; j < 4; j++)
      gload_lds16(Bbase + (size_t)(j * 32 + srow) * D_FF + k0 + scol_g, &Bs[j * 32 + srow][scol_l]);
    __syncthreads();
    #pragma unroll
    for (int kk = 0; kk < BK; kk += 32){
      const int ck = ((((kk >> 3) + (lane >> 4)) ^ (lane & 7)) * 8);
      bf16x8 a[4], b[4];
      #pragma unroll
      for (int i = 0; i < 4; i++)
        a[i] = *(const bf16x8*)&As[wm + i * 16 + frag_m][ck];
      #pragma unroll
      for (int j = 0; j < 4; j++)
        b[j] = *(const bf16x8*)&Bs[wn + j * 16 + frag_m][ck];
      #pragma unroll
      for (int i = 0; i < 4; i++)
        #pragma unroll
        for (int j = 0; j < 4; j++)
          acc[i][j] = __builtin_amdgcn_mfma_f32_16x16x32_bf16(a[i], b[j], acc[i][j], 0, 0, 0);
    }
  }

  const float* bias = b2 + (size_t)e * D_MODEL + (size_t)ntile * BN;
  #pragma unroll
  for (int i = 0; i < 4; i++){
    #pragma unroll
    for (int r = 0; r < 4; r++){
      int mrel = wm + i * 16 + (lane >> 4) * 4 + r;
      int m = mtile * BM + mrel;
      if (m >= count) continue;
      int slot = off + m;
      float g = bucket_gate[slot];
      int token = bucket_token[slot];
      float* orow = out + (size_t)token * D_MODEL + (size_t)ntile * BN;
      #pragma unroll
      for (int j = 0; j < 4; j++){
        int nrel = wn + j * 16 + (lane & 15);
        atomicAdd(&orow[nrel], g * (acc[i][j][r] + bias[nrel]));
      }
    }
  }
}

// ---------------- launch ----------------

extern "C" void kernel_launch(void* const* d_in, const int* in_sizes, int n_in,
                              void* d_out, int out_size, void* d_ws, size_t ws_size,
                              hipStream_t stream) {
  (void)in_sizes; (void)n_in; (void)ws_size;
  const float* x  = (const float*)d_in[0];
  const float* Wr = (const float*)d_in[1];
  const float* br = (const float*)d_in[2];
  const float* W1 = (const float*)d_in[3];
  const float* b1 = (const float*)d_in[4];
  const float* W2 = (const float*)d_in[5];
  const float* b2 = (const float*)d_in[6];
  float* out = (float*)d_out;

  char* ws = (char*)d_ws;
  size_t p = 0;
  auto alloc = [&](size_t bytes) -> void* {
    void* r = ws + p;
    p = (p + bytes + 255) & ~(size_t)255;
    return r;
  };

  int*   counts       = (int*)  alloc(N_EXPERTS * sizeof(int));
  int*   offsets      = (int*)  alloc(N_EXPERTS * sizeof(int));
  int*   cursor       = (int*)  alloc(N_EXPERTS * sizeof(int));
  int*   tile_e       = (int*)  alloc(MAXTILES * sizeof(int));
  int*   tile_m       = (int*)  alloc(MAXTILES * sizeof(int));
  int*   topk_idx     = (int*)  alloc((size_t)NTOK * 2 * sizeof(int));
  float* topk_gate    = (float*)alloc((size_t)NTOK * 2 * sizeof(float));
  int*   bucket_token = (int*)  alloc((size_t)NSLOT * sizeof(int));
  float* bucket_gate  = (float*)alloc((size_t)NSLOT * sizeof(float));
  unsigned short* xb  = (unsigned short*)alloc((size_t)NTOK * D_MODEL * 2);
  unsigned short* W1t = (unsigned short*)alloc((size_t)N_EXPERTS * D_MODEL * D_FF * 2);
  unsigned short* W2t = (unsigned short*)alloc((size_t)N_EXPERTS * D_MODEL * D_FF * 2);
  unsigned short* hb  = (unsigned short*)alloc((size_t)NSLOT * D_FF * 2);

  hipMemsetAsync(counts, 0, N_EXPERTS * sizeof(int), stream);
  hipMemsetAsync(out, 0, (size_t)out_size, stream);

  // Transposes FIRST so nothing streams between gemm1 and gemm2 (keeps h
  // L3-resident for gemm2), and gemm1 reads recently-written xb/W1t.
  transpose_convert_kernel<<<dim3(D_MODEL / 64, D_FF / 64, N_EXPERTS), 256, 0, stream>>>(
      W2, W2t, D_FF, D_MODEL);
  transpose_convert_kernel<<<dim3(D_FF / 64, D_MODEL / 64, N_EXPERTS), 256, 0, stream>>>(
      W1, W1t, D_MODEL, D_FF);
  router_kernel<<<NTOK / 4, 256, 0, stream>>>(x, Wr, br, counts, topk_idx, topk_gate, xb);
  prefix_kernel<<<1, 256, 0, stream>>>(counts, offsets, cursor, tile_e, tile_m);
  assign_kernel<<<NTOK / 256, 256, 0, stream>>>(topk_idx, topk_gate, cursor,
                                                bucket_token, bucket_gate);
  gemm1_kernel<<<dim3(D_FF / BN, MAXTILES), 256, 0, stream>>>(
      xb, W1t, b1, bucket_token, offsets, counts, tile_e, tile_m, hb);
  gemm2_kernel<<<dim3(D_MODEL / BN, MAXTILES), 256, 0, stream>>>(
      hb, W2t, b2, bucket_gate, bucket_token, offsets, counts, tile_e, tile_m, out);
}

// Round 5
// 747.698 us; speedup vs baseline: 1.3801x; 1.3447x over previous
//
#include <hip/hip_runtime.h>
#include <cstdint>
#include <cstddef>

#define D_MODEL 1024
#define D_FF    4096
#define N_EXPERTS 8
#define TOPK_    2
#define NTOK    8192
#define NSLOT   (NTOK*TOPK_)
#define MAXTILES 136

#define BM 128
#define BN 128
#define BK 64

typedef __attribute__((ext_vector_type(8))) short bf16x8;
typedef __attribute__((ext_vector_type(4))) float f32x4;
typedef unsigned int u32;

__device__ __forceinline__ unsigned short f2bf(float f){
  union { float f; u32 u; } v; v.f = f;
  u32 u = v.u;
  u32 r = (u + 0x7FFFu + ((u >> 16) & 1u)) >> 16;
  return (unsigned short)r;
}

__device__ __forceinline__ float bf2f(unsigned short s){
  union { u32 u; float f; } v; v.u = (u32)s << 16; return v.f;
}

// gelu via Abramowitz-Stegun 7.1.26 erf, |err| <= 1.5e-7 abs.
__device__ __forceinline__ float gelu_fast(float x){
  float z = fabsf(x) * 0.70710678118654752f;
  float t = __builtin_amdgcn_rcpf(fmaf(0.3275911f, z, 1.0f));
  float poly = t * (0.254829592f + t * (-0.284496736f + t * (1.421413741f +
               t * (-1.453152027f + t * 1.061405429f))));
  float e = __expf(-z * z);
  float erf_abs = fmaf(-poly, e, 1.0f);
  float erfv = copysignf(erf_abs, x);
  return 0.5f * x * (1.0f + erfv);
}

__device__ __forceinline__ void gload_lds16(const void* g, void* l){
  __builtin_amdgcn_global_load_lds(
      (const __attribute__((address_space(1))) u32*)g,
      (__attribute__((address_space(3))) u32*)l, 16, 0, 0);
}

// ---------------- prep: W1/W2 transpose+convert AND router, ONE launch -------
// blocks [0,8192):      W2 [E][4096][1024] fp32 -> W2t [E][1024][4096] bf16
// blocks [8192,16384):  W1 [E][1024][4096] fp32 -> W1t [E][4096][1024] bf16
// blocks [16384,18432): router, 4 tokens/block (1 wave each) + x -> bf16
// Merging kills 2 graph nodes + the counts memset (counts derived later).

__global__ __launch_bounds__(256) void prep_kernel(
    const float* __restrict__ W1, const float* __restrict__ W2,
    const float* __restrict__ x,  const float* __restrict__ Wr,
    const float* __restrict__ br,
    unsigned short* __restrict__ W1t, unsigned short* __restrict__ W2t,
    unsigned short* __restrict__ xb,
    int* __restrict__ topk_idx, float* __restrict__ topk_gate){
  __shared__ float tile[64][65];
  const int bid = blockIdx.x;
  const int tid = threadIdx.x;

  if (bid < 16384){
    const float* in; unsigned short* out; int R, C, c0, r0, e;
    if (bid < 8192){
      e  = bid >> 10;              // 1024 tiles/expert: 16 (c) x 64 (r)
      int t = bid & 1023;
      c0 = (t & 15) * 64;
      r0 = (t >> 4) * 64;
      in = W2; out = W2t; R = D_FF; C = D_MODEL;
    } else {
      int b = bid - 8192;
      e  = b >> 10;                // 1024 tiles/expert: 64 (c) x 16 (r)
      int t = b & 1023;
      c0 = (t & 63) * 64;
      r0 = (t >> 6) * 64;
      in = W1; out = W1t; R = D_MODEL; C = D_FF;
    }
    const size_t base = (size_t)e * R * C;
    {
      const int r  = tid >> 4;
      const int c4 = (tid & 15) * 4;
      #pragma unroll
      for (int it = 0; it < 4; it++){
        int rr = r + it * 16;
        float4 v = *(const float4*)(in + base + (size_t)(r0 + rr) * C + c0 + c4);
        tile[rr][c4 + 0] = v.x;
        tile[rr][c4 + 1] = v.y;
        tile[rr][c4 + 2] = v.z;
        tile[rr][c4 + 3] = v.w;
      }
    }
    __syncthreads();
    {
      const int c  = tid >> 4;
      const int r4 = (tid & 15) * 4;
      #pragma unroll
      for (int it = 0; it < 4; it++){
        int cc = c + it * 16;
        ushort4 w;
        w.x = f2bf(tile[r4 + 0][cc]);
        w.y = f2bf(tile[r4 + 1][cc]);
        w.z = f2bf(tile[r4 + 2][cc]);
        w.w = f2bf(tile[r4 + 3][cc]);
        *(ushort4*)(out + base + (size_t)(c0 + cc) * R + r0 + r4) = w;
      }
    }
    return;
  }

  // ---- router ----
  const int n = (bid - 16384) * 4 + (tid >> 6);
  const int lane = tid & 63;
  const float* xr = x + (size_t)n * D_MODEL;
  unsigned short* xbr = xb + (size_t)n * D_MODEL;
  float acc[N_EXPERTS];
  #pragma unroll
  for (int e = 0; e < N_EXPERTS; e++) acc[e] = 0.f;
  #pragma unroll
  for (int it = 0; it < 4; it++){
    int d = it * 256 + lane * 4;
    float4 v = *(const float4*)(xr + d);
    ushort4 w;
    w.x = f2bf(v.x); w.y = f2bf(v.y); w.z = f2bf(v.z); w.w = f2bf(v.w);
    *(ushort4*)(xbr + d) = w;
    const float* wr = Wr + (size_t)d * N_EXPERTS;
    const float* vv = &v.x;
    #pragma unroll
    for (int j = 0; j < 4; j++)
      #pragma unroll
      for (int e = 0; e < N_EXPERTS; e++)
        acc[e] = fmaf(vv[j], wr[j * N_EXPERTS + e], acc[e]);
  }
  #pragma unroll
  for (int e = 0; e < N_EXPERTS; e++){
    float v = acc[e];
    for (int o = 32; o > 0; o >>= 1) v += __shfl_xor(v, o, 64);
    acc[e] = v;
  }
  if (lane == 0){
    float logits[N_EXPERTS];
    float m = -1e30f;
    #pragma unroll
    for (int e = 0; e < N_EXPERTS; e++){
      logits[e] = acc[e] + br[e];
      m = fmaxf(m, logits[e]);
    }
    float p[N_EXPERTS]; float Z = 0.f;
    #pragma unroll
    for (int e = 0; e < N_EXPERTS; e++){ p[e] = expf(logits[e] - m); Z += p[e]; }
    #pragma unroll
    for (int e = 0; e < N_EXPERTS; e++) p[e] /= Z;
    int i0 = 0;
    #pragma unroll
    for (int e = 1; e < N_EXPERTS; e++) if (p[e] > p[i0]) i0 = e;
    int i1 = (i0 == 0) ? 1 : 0;
    #pragma unroll
    for (int e = 0; e < N_EXPERTS; e++){
      if (e == i0) continue;
      if (p[e] > p[i1]) i1 = e;
    }
    float s = p[i0] + p[i1] + 1e-9f;
    topk_idx[n * 2 + 0] = i0;
    topk_idx[n * 2 + 1] = i1;
    topk_gate[n * 2 + 0] = p[i0] / s;
    topk_gate[n * 2 + 1] = p[i1] / s;
  }
}

// ---------------- bookkeeping: counts+prefix+tiletable+assign, ONE block -----

__global__ __launch_bounds__(1024) void prefix_assign_kernel(
    const int* __restrict__ topk_idx,
    const float* __restrict__ topk_gate,
    int* __restrict__ offsets,           // [N_EXPERTS+1]
    int* __restrict__ tile_e,
    int* __restrict__ tile_m,
    int* __restrict__ bucket_token,
    float* __restrict__ bucket_gate,
    int* __restrict__ slot_of){
  __shared__ int scnt[N_EXPERTS];
  __shared__ int soff[N_EXPERTS + 1];
  __shared__ int scur[N_EXPERTS];
  const int tid = threadIdx.x;
  if (tid < N_EXPERTS) scnt[tid] = 0;
  __syncthreads();
  for (int t = tid; t < NTOK; t += 1024){
    atomicAdd(&scnt[topk_idx[t * 2 + 0]], 1);
    atomicAdd(&scnt[topk_idx[t * 2 + 1]], 1);
  }
  __syncthreads();
  if (tid == 0){
    int o = 0;
    #pragma unroll
    for (int e = 0; e < N_EXPERTS; e++){ soff[e] = o; scur[e] = o; o += scnt[e]; }
    soff[N_EXPERTS] = o;
  }
  __syncthreads();
  if (tid <= N_EXPERTS) offsets[tid] = soff[tid];
  if (tid < MAXTILES){
    int t = tid, te = -1, tm = 0, acc = 0;
    #pragma unroll
    for (int e = 0; e < N_EXPERTS; e++){
      int nt = (scnt[e] + BM - 1) / BM;
      if (te < 0 && t < acc + nt){ te = e; tm = t - acc; }
      acc += nt;
    }
    tile_e[tid] = te; tile_m[tid] = tm;
  }
  for (int t = tid; t < NTOK; t += 1024){
    #pragma unroll
    for (int k = 0; k < TOPK_; k++){
      int e = topk_idx[t * 2 + k];
      float g = topk_gate[t * 2 + k];
      int s = atomicAdd(&scur[e], 1);
      bucket_token[s] = t;
      bucket_gate[s] = g;
      slot_of[t * 2 + k] = s;
    }
  }
}

// ---------------- grouped GEMM 1: h = gelu(x @ W1 + b1) ----------------
// Round-0 verified structure + XCD swizzle + 4 blocks/CU.

__global__ __launch_bounds__(256, 4) void gemm1_kernel(
    const unsigned short* __restrict__ xb,
    const unsigned short* __restrict__ W1t,
    const float* __restrict__ b1,
    const int* __restrict__ bucket_token,
    const int* __restrict__ offsets,
    const int* __restrict__ tile_e,
    const int* __restrict__ tile_m,
    unsigned short* __restrict__ h){
  // XCD swizzle: 4352 blocks = 8 x 544; each XCD gets 17 mtiles x 32 ntiles.
  int f = blockIdx.y * 32 + blockIdx.x;
  f = (f & 7) * ((32 * MAXTILES) >> 3) + (f >> 3);
  const int e = tile_e[f / 32];
  if (e < 0) return;
  const int mtile = tile_m[f / 32];
  const int ntile = f % 32;
  const int off = offsets[e];
  const int count = offsets[e + 1] - off;

  __shared__ unsigned short As[BM][BK];
  __shared__ unsigned short Bs[BN][BK];

  const int tid  = threadIdx.x;
  const int lane = tid & 63;
  const int wave = tid >> 6;

  const int srow   = wave * 8 + (lane >> 3);
  const int scol_l = (lane & 7) * 8;
  const int scol_g = (((lane & 7) ^ (lane >> 3)) * 8);

  int arow[4];
  #pragma unroll
  for (int j = 0; j < 4; j++){
    int m = mtile * BM + j * 32 + srow;
    arow[j] = bucket_token[off + min(m, count - 1)];
  }
  const unsigned short* Bbase = W1t + ((size_t)e * D_FF + (size_t)ntile * BN) * D_MODEL;

  const f32x4 zero = {0.f, 0.f, 0.f, 0.f};
  f32x4 acc[4][4];
  #pragma unroll
  for (int i = 0; i < 4; i++)
    #pragma unroll
    for (int j = 0; j < 4; j++) acc[i][j] = zero;

  const int wm = (wave >> 1) * 64;
  const int wn = (wave & 1) * 64;
  const int frag_m = lane & 15;

  for (int k0 = 0; k0 < D_MODEL; k0 += BK){
    __syncthreads();
    #pragma unroll
    for (int j = 0; j < 4; j++)
      gload_lds16(xb + (size_t)arow[j] * D_MODEL + k0 + scol_g, &As[j * 32 + srow][scol_l]);
    #pragma unroll
    for (int j = 0; j < 4; j++)
      gload_lds16(Bbase + (size_t)(j * 32 + srow) * D_MODEL + k0 + scol_g, &Bs[j * 32 + srow][scol_l]);
    __syncthreads();
    #pragma unroll
    for (int kk = 0; kk < BK; kk += 32){
      const int ck = ((((kk >> 3) + (lane >> 4)) ^ (lane & 7)) * 8);
      bf16x8 a[4], b[4];
      #pragma unroll
      for (int i = 0; i < 4; i++)
        a[i] = *(const bf16x8*)&As[wm + i * 16 + frag_m][ck];
      #pragma unroll
      for (int j = 0; j < 4; j++)
        b[j] = *(const bf16x8*)&Bs[wn + j * 16 + frag_m][ck];
      #pragma unroll
      for (int i = 0; i < 4; i++)
        #pragma unroll
        for (int j = 0; j < 4; j++)
          acc[i][j] = __builtin_amdgcn_mfma_f32_16x16x32_bf16(a[i], b[j], acc[i][j], 0, 0, 0);
    }
  }

  const float* bias = b1 + (size_t)e * D_FF + (size_t)ntile * BN;
  #pragma unroll
  for (int i = 0; i < 4; i++){
    #pragma unroll
    for (int r = 0; r < 4; r++){
      int mrel = wm + i * 16 + (lane >> 4) * 4 + r;
      int m = mtile * BM + mrel;
      if (m >= count) continue;
      size_t hrow = (size_t)(off + m) * D_FF + (size_t)ntile * BN;
      #pragma unroll
      for (int j = 0; j < 4; j++){
        int nrel = wn + j * 16 + (lane & 15);
        float v = acc[i][j][r] + bias[nrel];
        h[hrow + nrel] = f2bf(gelu_fast(v));
      }
    }
  }
}

// ---------------- grouped GEMM 2: y[slot] = bf16( g * (h @ W2 + b2) ) --------

__global__ __launch_bounds__(256, 4) void gemm2_kernel(
    const unsigned short* __restrict__ h,
    const unsigned short* __restrict__ W2t,   // [E][1024][4096]
    const float* __restrict__ b2,
    const float* __restrict__ bucket_gate,
    const int* __restrict__ offsets,
    const int* __restrict__ tile_e,
    const int* __restrict__ tile_m,
    unsigned short* __restrict__ y){
  // XCD swizzle: 1088 blocks = 8 x 136.
  int f = blockIdx.y * 8 + blockIdx.x;
  f = (f & 7) * ((8 * MAXTILES) >> 3) + (f >> 3);
  const int e = tile_e[f / 8];
  if (e < 0) return;
  const int mtile = tile_m[f / 8];
  const int ntile = f % 8;
  const int off = offsets[e];
  const int count = offsets[e + 1] - off;

  __shared__ unsigned short As[BM][BK];
  __shared__ unsigned short Bs[BN][BK];

  const int tid  = threadIdx.x;
  const int lane = tid & 63;
  const int wave = tid >> 6;

  const int srow   = wave * 8 + (lane >> 3);
  const int scol_l = (lane & 7) * 8;
  const int scol_g = (((lane & 7) ^ (lane >> 3)) * 8);

  size_t aslot[4];
  #pragma unroll
  for (int j = 0; j < 4; j++){
    int m = mtile * BM + j * 32 + srow;
    aslot[j] = (size_t)(off + min(m, count - 1));
  }
  const unsigned short* Bbase = W2t + ((size_t)e * D_MODEL + (size_t)ntile * BN) * D_FF;

  const f32x4 zero = {0.f, 0.f, 0.f, 0.f};
  f32x4 acc[4][4];
  #pragma unroll
  for (int i = 0; i < 4; i++)
    #pragma unroll
    for (int j = 0; j < 4; j++) acc[i][j] = zero;

  const int wm = (wave >> 1) * 64;
  const int wn = (wave & 1) * 64;
  const int frag_m = lane & 15;

  for (int k0 = 0; k0 < D_FF; k0 += BK){
    __syncthreads();
    #pragma unroll
    for (int j = 0; j < 4; j++)
      gload_lds16(h + aslot[j] * D_FF + k0 + scol_g, &As[j * 32 + srow][scol_l]);
    #pragma unroll
    for (int j = 0; j < 4; j++)
      gload_lds16(Bbase + (size_t)(j * 32 + srow) * D_FF + k0 + scol_g, &Bs[j * 32 + srow][scol_l]);
    __syncthreads();
    #pragma unroll
    for (int kk = 0; kk < BK; kk += 32){
      const int ck = ((((kk >> 3) + (lane >> 4)) ^ (lane & 7)) * 8);
      bf16x8 a[4], b[4];
      #pragma unroll
      for (int i = 0; i < 4; i++)
        a[i] = *(const bf16x8*)&As[wm + i * 16 + frag_m][ck];
      #pragma unroll
      for (int j = 0; j < 4; j++)
        b[j] = *(const bf16x8*)&Bs[wn + j * 16 + frag_m][ck];
      #pragma unroll
      for (int i = 0; i < 4; i++)
        #pragma unroll
        for (int j = 0; j < 4; j++)
          acc[i][j] = __builtin_amdgcn_mfma_f32_16x16x32_bf16(a[i], b[j], acc[i][j], 0, 0, 0);
    }
  }

  const float* bias = b2 + (size_t)e * D_MODEL + (size_t)ntile * BN;
  #pragma unroll
  for (int i = 0; i < 4; i++){
    #pragma unroll
    for (int r = 0; r < 4; r++){
      int mrel = wm + i * 16 + (lane >> 4) * 4 + r;
      int m = mtile * BM + mrel;
      if (m >= count) continue;
      int slot = off + m;
      float g = bucket_gate[slot];
      unsigned short* yrow = y + (size_t)slot * D_MODEL + (size_t)ntile * BN;
      #pragma unroll
      for (int j = 0; j < 4; j++){
        int nrel = wn + j * 16 + (lane & 15);
        yrow[nrel] = f2bf(g * (acc[i][j][r] + bias[nrel]));
      }
    }
  }
}

// ---------------- combine: out[t] = y[slot0(t)] + y[slot1(t)] ----------------

__global__ __launch_bounds__(256) void combine_kernel(
    const unsigned short* __restrict__ y,
    const int* __restrict__ slot_of,
    float* __restrict__ out){
  const int t = blockIdx.x;
  const int d = threadIdx.x * 4;
  const int s0 = slot_of[t * 2 + 0];
  const int s1 = slot_of[t * 2 + 1];
  uint2 a = *(const uint2*)(y + (size_t)s0 * D_MODEL + d);
  uint2 b = *(const uint2*)(y + (size_t)s1 * D_MODEL + d);
  float4 r;
  r.x = bf2f((unsigned short)(a.x & 0xffff)) + bf2f((unsigned short)(b.x & 0xffff));
  r.y = bf2f((unsigned short)(a.x >> 16))    + bf2f((unsigned short)(b.x >> 16));
  r.z = bf2f((unsigned short)(a.y & 0xffff)) + bf2f((unsigned short)(b.y & 0xffff));
  r.w = bf2f((unsigned short)(a.y >> 16))    + bf2f((unsigned short)(b.y >> 16));
  *(float4*)(out + (size_t)t * D_MODEL + d) = r;
}

// ---------------- launch: 5 graph nodes, no memsets ----------------

extern "C" void kernel_launch(void* const* d_in, const int* in_sizes, int n_in,
                              void* d_out, int out_size, void* d_ws, size_t ws_size,
                              hipStream_t stream) {
  (void)in_sizes; (void)n_in; (void)ws_size; (void)out_size;
  const float* x  = (const float*)d_in[0];
  const float* Wr = (const float*)d_in[1];
  const float* br = (const float*)d_in[2];
  const float* W1 = (const float*)d_in[3];
  const float* b1 = (const float*)d_in[4];
  const float* W2 = (const float*)d_in[5];
  const float* b2 = (const float*)d_in[6];
  float* out = (float*)d_out;

  char* ws = (char*)d_ws;
  size_t p = 0;
  auto alloc = [&](size_t bytes) -> void* {
    void* r = ws + p;
    p = (p + bytes + 255) & ~(size_t)255;
    return r;
  };

  int*   offsets      = (int*)  alloc((N_EXPERTS + 1) * sizeof(int));
  int*   tile_e       = (int*)  alloc(MAXTILES * sizeof(int));
  int*   tile_m       = (int*)  alloc(MAXTILES * sizeof(int));
  int*   topk_idx     = (int*)  alloc((size_t)NTOK * 2 * sizeof(int));
  float* topk_gate    = (float*)alloc((size_t)NTOK * 2 * sizeof(float));
  int*   bucket_token = (int*)  alloc((size_t)NSLOT * sizeof(int));
  float* bucket_gate  = (float*)alloc((size_t)NSLOT * sizeof(float));
  int*   slot_of      = (int*)  alloc((size_t)NTOK * 2 * sizeof(int));
  unsigned short* xb  = (unsigned short*)alloc((size_t)NTOK * D_MODEL * 2);
  unsigned short* W1t = (unsigned short*)alloc((size_t)N_EXPERTS * D_MODEL * D_FF * 2);
  unsigned short* W2t = (unsigned short*)alloc((size_t)N_EXPERTS * D_MODEL * D_FF * 2);
  unsigned short* hb  = (unsigned short*)alloc((size_t)NSLOT * D_FF * 2);
  // y (bf16, 32 MB) aliases W1t (64 MB): W1t is dead once gemm1 completes.
  unsigned short* y = W1t;

  prep_kernel<<<16384 + NTOK / 4, 256, 0, stream>>>(
      W1, W2, x, Wr, br, W1t, W2t, xb, topk_idx, topk_gate);
  prefix_assign_kernel<<<1, 1024, 0, stream>>>(
      topk_idx, topk_gate, offsets, tile_e, tile_m,
      bucket_token, bucket_gate, slot_of);
  gemm1_kernel<<<dim3(D_FF / BN, MAXTILES), 256, 0, stream>>>(
      xb, W1t, b1, bucket_token, offsets, tile_e, tile_m, hb);
  gemm2_kernel<<<dim3(D_MODEL / BN, MAXTILES), 256, 0, stream>>>(
      hb, W2t, b2, bucket_gate, offsets, tile_e, tile_m, y);
  combine_kernel<<<NTOK, 256, 0, stream>>>(y, slot_of, out);
}

// Round 6
// 729.926 us; speedup vs baseline: 1.4137x; 1.0243x over previous
//
#include <hip/hip_runtime.h>
#include <cstdint>
#include <cstddef>

#define D_MODEL 1024
#define D_FF    4096
#define N_EXPERTS 8
#define TOPK_    2
#define NTOK    8192
#define NSLOT   (NTOK*TOPK_)
#define MAXTILES 136
#define NBLK    64      // bookkeeping blocks; NTOK/NBLK tokens each

#define BM 128
#define BN 128
#define BK 64

typedef __attribute__((ext_vector_type(8))) short bf16x8;
typedef __attribute__((ext_vector_type(4))) float f32x4;
typedef unsigned int u32;

__device__ __forceinline__ unsigned short f2bf(float f){
  union { float f; u32 u; } v; v.f = f;
  u32 u = v.u;
  u32 r = (u + 0x7FFFu + ((u >> 16) & 1u)) >> 16;
  return (unsigned short)r;
}

__device__ __forceinline__ float bf2f(unsigned short s){
  union { u32 u; float f; } v; v.u = (u32)s << 16; return v.f;
}

// gelu via Abramowitz-Stegun 7.1.26 erf, |err| <= 1.5e-7 abs.
__device__ __forceinline__ float gelu_fast(float x){
  float z = fabsf(x) * 0.70710678118654752f;
  float t = __builtin_amdgcn_rcpf(fmaf(0.3275911f, z, 1.0f));
  float poly = t * (0.254829592f + t * (-0.284496736f + t * (1.421413741f +
               t * (-1.453152027f + t * 1.061405429f))));
  float e = __expf(-z * z);
  float erf_abs = fmaf(-poly, e, 1.0f);
  float erfv = copysignf(erf_abs, x);
  return 0.5f * x * (1.0f + erfv);
}

__device__ __forceinline__ void gload_lds16(const void* g, void* l){
  __builtin_amdgcn_global_load_lds(
      (const __attribute__((address_space(1))) u32*)g,
      (__attribute__((address_space(3))) u32*)l, 16, 0, 0);
}

// ---------------- prep: W1/W2 transpose+convert AND router, ONE launch -------
// blocks [0,8192):      W2 [E][4096][1024] fp32 -> W2t [E][1024][4096] bf16
// blocks [8192,16384):  W1 [E][1024][4096] fp32 -> W1t [E][4096][1024] bf16
// blocks [16384,18432): router, 4 tokens/block (1 wave each) + x -> bf16

__global__ __launch_bounds__(256) void prep_kernel(
    const float* __restrict__ W1, const float* __restrict__ W2,
    const float* __restrict__ x,  const float* __restrict__ Wr,
    const float* __restrict__ br,
    unsigned short* __restrict__ W1t, unsigned short* __restrict__ W2t,
    unsigned short* __restrict__ xb,
    int* __restrict__ topk_idx, float* __restrict__ topk_gate){
  __shared__ float tile[64][65];
  const int bid = blockIdx.x;
  const int tid = threadIdx.x;

  if (bid < 16384){
    const float* in; unsigned short* out; int R, C, c0, r0, e;
    if (bid < 8192){
      e  = bid >> 10;              // 1024 tiles/expert: 16 (c) x 64 (r)
      int t = bid & 1023;
      c0 = (t & 15) * 64;
      r0 = (t >> 4) * 64;
      in = W2; out = W2t; R = D_FF; C = D_MODEL;
    } else {
      int b = bid - 8192;
      e  = b >> 10;                // 1024 tiles/expert: 64 (c) x 16 (r)
      int t = b & 1023;
      c0 = (t & 63) * 64;
      r0 = (t >> 6) * 64;
      in = W1; out = W1t; R = D_MODEL; C = D_FF;
    }
    const size_t base = (size_t)e * R * C;
    {
      const int r  = tid >> 4;
      const int c4 = (tid & 15) * 4;
      #pragma unroll
      for (int it = 0; it < 4; it++){
        int rr = r + it * 16;
        float4 v = *(const float4*)(in + base + (size_t)(r0 + rr) * C + c0 + c4);
        tile[rr][c4 + 0] = v.x;
        tile[rr][c4 + 1] = v.y;
        tile[rr][c4 + 2] = v.z;
        tile[rr][c4 + 3] = v.w;
      }
    }
    __syncthreads();
    {
      const int c  = tid >> 4;
      const int r4 = (tid & 15) * 4;
      #pragma unroll
      for (int it = 0; it < 4; it++){
        int cc = c + it * 16;
        ushort4 w;
        w.x = f2bf(tile[r4 + 0][cc]);
        w.y = f2bf(tile[r4 + 1][cc]);
        w.z = f2bf(tile[r4 + 2][cc]);
        w.w = f2bf(tile[r4 + 3][cc]);
        *(ushort4*)(out + base + (size_t)(c0 + cc) * R + r0 + r4) = w;
      }
    }
    return;
  }

  // ---- router ----
  const int n = (bid - 16384) * 4 + (tid >> 6);
  const int lane = tid & 63;
  const float* xr = x + (size_t)n * D_MODEL;
  unsigned short* xbr = xb + (size_t)n * D_MODEL;
  float acc[N_EXPERTS];
  #pragma unroll
  for (int e = 0; e < N_EXPERTS; e++) acc[e] = 0.f;
  #pragma unroll
  for (int it = 0; it < 4; it++){
    int d = it * 256 + lane * 4;
    float4 v = *(const float4*)(xr + d);
    ushort4 w;
    w.x = f2bf(v.x); w.y = f2bf(v.y); w.z = f2bf(v.z); w.w = f2bf(v.w);
    *(ushort4*)(xbr + d) = w;
    const float* wr = Wr + (size_t)d * N_EXPERTS;
    const float* vv = &v.x;
    #pragma unroll
    for (int j = 0; j < 4; j++)
      #pragma unroll
      for (int e = 0; e < N_EXPERTS; e++)
        acc[e] = fmaf(vv[j], wr[j * N_EXPERTS + e], acc[e]);
  }
  #pragma unroll
  for (int e = 0; e < N_EXPERTS; e++){
    float v = acc[e];
    for (int o = 32; o > 0; o >>= 1) v += __shfl_xor(v, o, 64);
    acc[e] = v;
  }
  if (lane == 0){
    float logits[N_EXPERTS];
    float m = -1e30f;
    #pragma unroll
    for (int e = 0; e < N_EXPERTS; e++){
      logits[e] = acc[e] + br[e];
      m = fmaxf(m, logits[e]);
    }
    float p[N_EXPERTS]; float Z = 0.f;
    #pragma unroll
    for (int e = 0; e < N_EXPERTS; e++){ p[e] = expf(logits[e] - m); Z += p[e]; }
    #pragma unroll
    for (int e = 0; e < N_EXPERTS; e++) p[e] /= Z;
    int i0 = 0;
    #pragma unroll
    for (int e = 1; e < N_EXPERTS; e++) if (p[e] > p[i0]) i0 = e;
    int i1 = (i0 == 0) ? 1 : 0;
    #pragma unroll
    for (int e = 0; e < N_EXPERTS; e++){
      if (e == i0) continue;
      if (p[e] > p[i1]) i1 = e;
    }
    float s = p[i0] + p[i1] + 1e-9f;
    topk_idx[n * 2 + 0] = i0;
    topk_idx[n * 2 + 1] = i1;
    topk_gate[n * 2 + 0] = p[i0] / s;
    topk_gate[n * 2 + 1] = p[i1] / s;
  }
}

// ---------------- bookkeeping, decontended: hist (64 blocks) + assign --------
// Round-5's single-block version did 65536 LDS atomics on 8 addresses on ONE
// CU — suspected ~200 µs serial bubble. Here: per-block histograms, then
// ballot-ranked assignment with ZERO contended atomics.

__global__ __launch_bounds__(256) void hist_kernel(
    const int* __restrict__ topk_idx,
    int* __restrict__ blockhist){         // [NBLK][8]
  __shared__ int sh[N_EXPERTS];
  const int tid = threadIdx.x;
  if (tid < N_EXPERTS) sh[tid] = 0;
  __syncthreads();
  const int t0 = blockIdx.x * (NTOK / NBLK);
  if (tid < (NTOK / NBLK)){
    atomicAdd(&sh[topk_idx[(t0 + tid) * 2 + 0]], 1);
    atomicAdd(&sh[topk_idx[(t0 + tid) * 2 + 1]], 1);
  }
  __syncthreads();
  if (tid < N_EXPERTS) blockhist[blockIdx.x * N_EXPERTS + tid] = sh[tid];
}

__global__ __launch_bounds__(256) void assign_kernel(
    const int* __restrict__ topk_idx,
    const float* __restrict__ topk_gate,
    const int* __restrict__ blockhist,    // [NBLK][8]
    int* __restrict__ offsets,            // [N_EXPERTS+1]
    int* __restrict__ tile_e,
    int* __restrict__ tile_m,
    int* __restrict__ bucket_token,
    float* __restrict__ bucket_gate,
    int* __restrict__ slot_of){
  __shared__ int bh[NBLK * N_EXPERTS];
  __shared__ int stot[N_EXPERTS], spre[N_EXPERTS], soff[N_EXPERTS + 1];
  __shared__ int wcnt[4][N_EXPERTS];
  const int tid = threadIdx.x;
  const int bid = blockIdx.x;
  for (int i = tid; i < NBLK * N_EXPERTS; i += 256) bh[i] = blockhist[i];
  __syncthreads();
  if (tid < N_EXPERTS){
    int pre = 0, tot = 0;
    for (int b = 0; b < NBLK; b++){
      int v = bh[b * N_EXPERTS + tid];
      if (b < bid) pre += v;
      tot += v;
    }
    stot[tid] = tot; spre[tid] = pre;
  }
  __syncthreads();
  if (tid == 0){
    int o = 0;
    #pragma unroll
    for (int e = 0; e < N_EXPERTS; e++){ soff[e] = o; o += stot[e]; }
    soff[N_EXPERTS] = o;
  }
  __syncthreads();

  // my entry: 256 threads = 128 tokens x 2 choices, wave-ordered
  const int t = bid * (NTOK / NBLK) + (tid >> 1);
  const int k = tid & 1;
  const int myE = topk_idx[t * 2 + k];
  const float g = topk_gate[t * 2 + k];
  const int lane = tid & 63;
  const int w = tid >> 6;
  const unsigned long long lt = (1ULL << lane) - 1ULL;
  int wrank = 0;
  #pragma unroll
  for (int e = 0; e < N_EXPERTS; e++){
    unsigned long long m = __ballot(myE == e);
    if (myE == e) wrank = __popcll(m & lt);
    if (lane == 0) wcnt[w][e] = __popcll(m);
  }
  __syncthreads();
  int wpre = 0;
  #pragma unroll
  for (int ww = 0; ww < 4; ww++) if (ww < w) wpre += wcnt[ww][myE];
  const int slot = soff[myE] + spre[myE] + wpre + wrank;
  bucket_token[slot] = t;
  bucket_gate[slot] = g;
  slot_of[t * 2 + k] = slot;

  if (bid == 0){
    if (tid <= N_EXPERTS) offsets[tid] = soff[tid];
    if (tid < MAXTILES){
      int tt = tid, te = -1, tm = 0, acc = 0;
      #pragma unroll
      for (int e = 0; e < N_EXPERTS; e++){
        int nt = (stot[e] + BM - 1) / BM;
        if (te < 0 && tt < acc + nt){ te = e; tm = tt - acc; }
        acc += nt;
      }
      tile_e[tid] = te; tile_m[tid] = tm;
    }
  }
}

// ---------------- grouped GEMM 1: h = gelu(x @ W1 + b1) ----------------
// Round-0 verified structure + XCD swizzle + 4 blocks/CU.

__global__ __launch_bounds__(256, 4) void gemm1_kernel(
    const unsigned short* __restrict__ xb,
    const unsigned short* __restrict__ W1t,
    const float* __restrict__ b1,
    const int* __restrict__ bucket_token,
    const int* __restrict__ offsets,
    const int* __restrict__ tile_e,
    const int* __restrict__ tile_m,
    unsigned short* __restrict__ h){
  // XCD swizzle: 4352 blocks = 8 x 544; each XCD gets 17 mtiles x 32 ntiles.
  int f = blockIdx.y * 32 + blockIdx.x;
  f = (f & 7) * ((32 * MAXTILES) >> 3) + (f >> 3);
  const int e = tile_e[f / 32];
  if (e < 0) return;
  const int mtile = tile_m[f / 32];
  const int ntile = f % 32;
  const int off = offsets[e];
  const int count = offsets[e + 1] - off;

  __shared__ unsigned short As[BM][BK];
  __shared__ unsigned short Bs[BN][BK];

  const int tid  = threadIdx.x;
  const int lane = tid & 63;
  const int wave = tid >> 6;

  const int srow   = wave * 8 + (lane >> 3);
  const int scol_l = (lane & 7) * 8;
  const int scol_g = (((lane & 7) ^ (lane >> 3)) * 8);

  int arow[4];
  #pragma unroll
  for (int j = 0; j < 4; j++){
    int m = mtile * BM + j * 32 + srow;
    arow[j] = bucket_token[off + min(m, count - 1)];
  }
  const unsigned short* Bbase = W1t + ((size_t)e * D_FF + (size_t)ntile * BN) * D_MODEL;

  const f32x4 zero = {0.f, 0.f, 0.f, 0.f};
  f32x4 acc[4][4];
  #pragma unroll
  for (int i = 0; i < 4; i++)
    #pragma unroll
    for (int j = 0; j < 4; j++) acc[i][j] = zero;

  const int wm = (wave >> 1) * 64;
  const int wn = (wave & 1) * 64;
  const int frag_m = lane & 15;

  for (int k0 = 0; k0 < D_MODEL; k0 += BK){
    __syncthreads();
    #pragma unroll
    for (int j = 0; j < 4; j++)
      gload_lds16(xb + (size_t)arow[j] * D_MODEL + k0 + scol_g, &As[j * 32 + srow][scol_l]);
    #pragma unroll
    for (int j = 0; j < 4; j++)
      gload_lds16(Bbase + (size_t)(j * 32 + srow) * D_MODEL + k0 + scol_g, &Bs[j * 32 + srow][scol_l]);
    __syncthreads();
    #pragma unroll
    for (int kk = 0; kk < BK; kk += 32){
      const int ck = ((((kk >> 3) + (lane >> 4)) ^ (lane & 7)) * 8);
      bf16x8 a[4], b[4];
      #pragma unroll
      for (int i = 0; i < 4; i++)
        a[i] = *(const bf16x8*)&As[wm + i * 16 + frag_m][ck];
      #pragma unroll
      for (int j = 0; j < 4; j++)
        b[j] = *(const bf16x8*)&Bs[wn + j * 16 + frag_m][ck];
      #pragma unroll
      for (int i = 0; i < 4; i++)
        #pragma unroll
        for (int j = 0; j < 4; j++)
          acc[i][j] = __builtin_amdgcn_mfma_f32_16x16x32_bf16(a[i], b[j], acc[i][j], 0, 0, 0);
    }
  }

  const float* bias = b1 + (size_t)e * D_FF + (size_t)ntile * BN;
  #pragma unroll
  for (int i = 0; i < 4; i++){
    #pragma unroll
    for (int r = 0; r < 4; r++){
      int mrel = wm + i * 16 + (lane >> 4) * 4 + r;
      int m = mtile * BM + mrel;
      if (m >= count) continue;
      size_t hrow = (size_t)(off + m) * D_FF + (size_t)ntile * BN;
      #pragma unroll
      for (int j = 0; j < 4; j++){
        int nrel = wn + j * 16 + (lane & 15);
        float v = acc[i][j][r] + bias[nrel];
        h[hrow + nrel] = f2bf(gelu_fast(v));
      }
    }
  }
}

// ---------------- grouped GEMM 2: y[slot] = bf16( g * (h @ W2 + b2) ) --------

__global__ __launch_bounds__(256, 4) void gemm2_kernel(
    const unsigned short* __restrict__ h,
    const unsigned short* __restrict__ W2t,   // [E][1024][4096]
    const float* __restrict__ b2,
    const float* __restrict__ bucket_gate,
    const int* __restrict__ offsets,
    const int* __restrict__ tile_e,
    const int* __restrict__ tile_m,
    unsigned short* __restrict__ y){
  // XCD swizzle: 1088 blocks = 8 x 136.
  int f = blockIdx.y * 8 + blockIdx.x;
  f = (f & 7) * ((8 * MAXTILES) >> 3) + (f >> 3);
  const int e = tile_e[f / 8];
  if (e < 0) return;
  const int mtile = tile_m[f / 8];
  const int ntile = f % 8;
  const int off = offsets[e];
  const int count = offsets[e + 1] - off;

  __shared__ unsigned short As[BM][BK];
  __shared__ unsigned short Bs[BN][BK];

  const int tid  = threadIdx.x;
  const int lane = tid & 63;
  const int wave = tid >> 6;

  const int srow   = wave * 8 + (lane >> 3);
  const int scol_l = (lane & 7) * 8;
  const int scol_g = (((lane & 7) ^ (lane >> 3)) * 8);

  size_t aslot[4];
  #pragma unroll
  for (int j = 0; j < 4; j++){
    int m = mtile * BM + j * 32 + srow;
    aslot[j] = (size_t)(off + min(m, count - 1));
  }
  const unsigned short* Bbase = W2t + ((size_t)e * D_MODEL + (size_t)ntile * BN) * D_FF;

  const f32x4 zero = {0.f, 0.f, 0.f, 0.f};
  f32x4 acc[4][4];
  #pragma unroll
  for (int i = 0; i < 4; i++)
    #pragma unroll
    for (int j = 0; j < 4; j++) acc[i][j] = zero;

  const int wm = (wave >> 1) * 64;
  const int wn = (wave & 1) * 64;
  const int frag_m = lane & 15;

  for (int k0 = 0; k0 < D_FF; k0 += BK){
    __syncthreads();
    #pragma unroll
    for (int j = 0; j < 4; j++)
      gload_lds16(h + aslot[j] * D_FF + k0 + scol_g, &As[j * 32 + srow][scol_l]);
    #pragma unroll
    for (int j = 0; j < 4; j++)
      gload_lds16(Bbase + (size_t)(j * 32 + srow) * D_FF + k0 + scol_g, &Bs[j * 32 + srow][scol_l]);
    __syncthreads();
    #pragma unroll
    for (int kk = 0; kk < BK; kk += 32){
      const int ck = ((((kk >> 3) + (lane >> 4)) ^ (lane & 7)) * 8);
      bf16x8 a[4], b[4];
      #pragma unroll
      for (int i = 0; i < 4; i++)
        a[i] = *(const bf16x8*)&As[wm + i * 16 + frag_m][ck];
      #pragma unroll
      for (int j = 0; j < 4; j++)
        b[j] = *(const bf16x8*)&Bs[wn + j * 16 + frag_m][ck];
      #pragma unroll
      for (int i = 0; i < 4; i++)
        #pragma unroll
        for (int j = 0; j < 4; j++)
          acc[i][j] = __builtin_amdgcn_mfma_f32_16x16x32_bf16(a[i], b[j], acc[i][j], 0, 0, 0);
    }
  }

  const float* bias = b2 + (size_t)e * D_MODEL + (size_t)ntile * BN;
  #pragma unroll
  for (int i = 0; i < 4; i++){
    #pragma unroll
    for (int r = 0; r < 4; r++){
      int mrel = wm + i * 16 + (lane >> 4) * 4 + r;
      int m = mtile * BM + mrel;
      if (m >= count) continue;
      int slot = off + m;
      float g = bucket_gate[slot];
      unsigned short* yrow = y + (size_t)slot * D_MODEL + (size_t)ntile * BN;
      #pragma unroll
      for (int j = 0; j < 4; j++){
        int nrel = wn + j * 16 + (lane & 15);
        yrow[nrel] = f2bf(g * (acc[i][j][r] + bias[nrel]));
      }
    }
  }
}

// ---------------- combine: out[t] = y[slot0(t)] + y[slot1(t)] ----------------

__global__ __launch_bounds__(256) void combine_kernel(
    const unsigned short* __restrict__ y,
    const int* __restrict__ slot_of,
    float* __restrict__ out){
  const int t = blockIdx.x;
  const int d = threadIdx.x * 4;
  const int s0 = slot_of[t * 2 + 0];
  const int s1 = slot_of[t * 2 + 1];
  uint2 a = *(const uint2*)(y + (size_t)s0 * D_MODEL + d);
  uint2 b = *(const uint2*)(y + (size_t)s1 * D_MODEL + d);
  float4 r;
  r.x = bf2f((unsigned short)(a.x & 0xffff)) + bf2f((unsigned short)(b.x & 0xffff));
  r.y = bf2f((unsigned short)(a.x >> 16))    + bf2f((unsigned short)(b.x >> 16));
  r.z = bf2f((unsigned short)(a.y & 0xffff)) + bf2f((unsigned short)(b.y & 0xffff));
  r.w = bf2f((unsigned short)(a.y >> 16))    + bf2f((unsigned short)(b.y >> 16));
  *(float4*)(out + (size_t)t * D_MODEL + d) = r;
}

// ---------------- launch: 6 graph nodes, no memsets ----------------

extern "C" void kernel_launch(void* const* d_in, const int* in_sizes, int n_in,
                              void* d_out, int out_size, void* d_ws, size_t ws_size,
                              hipStream_t stream) {
  (void)in_sizes; (void)n_in; (void)ws_size; (void)out_size;
  const float* x  = (const float*)d_in[0];
  const float* Wr = (const float*)d_in[1];
  const float* br = (const float*)d_in[2];
  const float* W1 = (const float*)d_in[3];
  const float* b1 = (const float*)d_in[4];
  const float* W2 = (const float*)d_in[5];
  const float* b2 = (const float*)d_in[6];
  float* out = (float*)d_out;

  char* ws = (char*)d_ws;
  size_t p = 0;
  auto alloc = [&](size_t bytes) -> void* {
    void* r = ws + p;
    p = (p + bytes + 255) & ~(size_t)255;
    return r;
  };

  int*   offsets      = (int*)  alloc((N_EXPERTS + 1) * sizeof(int));
  int*   blockhist    = (int*)  alloc((size_t)NBLK * N_EXPERTS * sizeof(int));
  int*   tile_e       = (int*)  alloc(MAXTILES * sizeof(int));
  int*   tile_m       = (int*)  alloc(MAXTILES * sizeof(int));
  int*   topk_idx     = (int*)  alloc((size_t)NTOK * 2 * sizeof(int));
  float* topk_gate    = (float*)alloc((size_t)NTOK * 2 * sizeof(float));
  int*   bucket_token = (int*)  alloc((size_t)NSLOT * sizeof(int));
  float* bucket_gate  = (float*)alloc((size_t)NSLOT * sizeof(float));
  int*   slot_of      = (int*)  alloc((size_t)NTOK * 2 * sizeof(int));
  unsigned short* xb  = (unsigned short*)alloc((size_t)NTOK * D_MODEL * 2);
  unsigned short* W1t = (unsigned short*)alloc((size_t)N_EXPERTS * D_MODEL * D_FF * 2);
  unsigned short* W2t = (unsigned short*)alloc((size_t)N_EXPERTS * D_MODEL * D_FF * 2);
  unsigned short* hb  = (unsigned short*)alloc((size_t)NSLOT * D_FF * 2);
  // y (bf16, 32 MB) aliases W1t (64 MB): W1t is dead once gemm1 completes.
  unsigned short* y = W1t;

  prep_kernel<<<16384 + NTOK / 4, 256, 0, stream>>>(
      W1, W2, x, Wr, br, W1t, W2t, xb, topk_idx, topk_gate);
  hist_kernel<<<NBLK, 256, 0, stream>>>(topk_idx, blockhist);
  assign_kernel<<<NBLK, 256, 0, stream>>>(
      topk_idx, topk_gate, blockhist, offsets, tile_e, tile_m,
      bucket_token, bucket_gate, slot_of);
  gemm1_kernel<<<dim3(D_FF / BN, MAXTILES), 256, 0, stream>>>(
      xb, W1t, b1, bucket_token, offsets, tile_e, tile_m, hb);
  gemm2_kernel<<<dim3(D_MODEL / BN, MAXTILES), 256, 0, stream>>>(
      hb, W2t, b2, bucket_gate, offsets, tile_e, tile_m, y);
  combine_kernel<<<NTOK, 256, 0, stream>>>(y, slot_of, out);
}